// Round 2
// baseline (1132.503 us; speedup 1.0000x reference)
//
#include <hip/hip_runtime.h>
#include <hip/hip_bf16.h>

#define A_N 16
#define B_N 8192
#define O_N 128
#define ACT_N 16
#define H_N 128
#define NH_N 4
#define D_N 32
#define IN_N 144
#define NEGV -1e9f

// -------------------------------------------------------------------------
// ws layout (floats):
//   0    : gsum / mean [A*IN] (2304)
//   2304 : gsq  / rstd [A*IN] (2304)
//   4608 : 5 slice buffers of A*Bc*H floats each: sa, se, keys, vals, sel
//          (`other` reuses sa). Bc chosen at runtime so this fits ws_size.
// -------------------------------------------------------------------------

__global__ __launch_bounds__(256) void k_zero(float* p, int n) {
    int i = blockIdx.x * 256 + threadIdx.x;
    if (i < n) p[i] = 0.f;
}

// Per-agent per-feature sum/sumsq over full batch. grid = A*8 (1024 rows each).
__global__ __launch_bounds__(256) void k_stats(const float* __restrict__ obs,
                                               const float* __restrict__ act,
                                               float* __restrict__ gsum,
                                               float* __restrict__ gsq) {
    __shared__ float ssum[IN_N];
    __shared__ float ssq[IN_N];
    int a = blockIdx.x >> 3;
    int chunk = blockIdx.x & 7;
    int t = threadIdx.x;
    if (t < IN_N) { ssum[t] = 0.f; ssq[t] = 0.f; }
    __syncthreads();
    int b0 = chunk * 1024;
    const float* ob = obs + ((size_t)a * B_N + b0) * O_N;
    for (int idx = t; idx < 1024 * O_N; idx += 256) {
        float v = ob[idx];
        int f = idx & (O_N - 1);
        atomicAdd(&ssum[f], v);
        atomicAdd(&ssq[f], v * v);
    }
    const float* ac = act + ((size_t)a * B_N + b0) * ACT_N;
    for (int idx = t; idx < 1024 * ACT_N; idx += 256) {
        float v = ac[idx];
        int f = idx & (ACT_N - 1);
        atomicAdd(&ssum[O_N + f], v);
        atomicAdd(&ssq[O_N + f], v * v);
    }
    __syncthreads();
    if (t < IN_N) {
        atomicAdd(&gsum[a * IN_N + t], ssum[t]);
        atomicAdd(&gsq[a * IN_N + t], ssq[t]);
    }
}

__global__ __launch_bounds__(256) void k_finalize(float* gsum, float* gsq) {
    int i = blockIdx.x * 256 + threadIdx.x;
    if (i < A_N * IN_N) {
        const float invB = 1.f / (float)B_N;
        float m = gsum[i] * invB;
        float ex2 = gsq[i] * invB;
        float v = ex2 - m * m;
        v = fmaxf(v, 0.f);
        gsum[i] = m;
        gsq[i] = rsqrtf(v + 1e-5f);
    }
}

// Generic fp32 GEMM over a 64(batch) x 128(out) tile per block.
// mode 0: x = BN(concat(obs, actions)) from GLOBAL batch (b0g + local), W [A,K,H]
// mode 1: x = xin (slice-local [A,Bc,H]), W [NH,H,D] interleaved to [K, NH*D]
// Output is slice-local [A,Bc,H].
#define CK 48
__global__ __launch_bounds__(256) void k_gemm(
    const float* __restrict__ obs, const float* __restrict__ act,
    const float* __restrict__ xin,
    const float* __restrict__ mean, const float* __restrict__ rstd,
    const float* __restrict__ W, const float* __restrict__ bias,
    int bias_per_agent, int K, int mode, int do_act,
    int b0g, int Bc,
    float* __restrict__ out) {
    __shared__ float xs[64 * IN_N];   // 36 KB max
    __shared__ float Ws[CK * H_N];    // 24 KB
    int a = blockIdx.y;
    int b0 = blockIdx.x * 64;   // slice-local
    int t = threadIdx.x;

    if (mode == 0) {
        for (int idx = t; idx < 64 * K; idx += 256) {
            int r = idx / K;
            int i = idx - r * K;
            size_t row = (size_t)a * B_N + b0g + b0 + r;  // global batch row
            float v = (i < O_N) ? obs[row * O_N + i] : act[row * ACT_N + (i - O_N)];
            v = (v - mean[a * IN_N + i]) * rstd[a * IN_N + i];
            xs[idx] = v;
        }
    } else {
        for (int idx = t; idx < 64 * H_N; idx += 256) {
            xs[idx] = xin[((size_t)a * Bc + b0 + (idx >> 7)) * H_N + (idx & 127)];
        }
    }

    int tx = t & 31, ty = t >> 5;
    float acc[8][4];
#pragma unroll
    for (int j = 0; j < 8; ++j)
#pragma unroll
        for (int c = 0; c < 4; ++c) acc[j][c] = 0.f;

    for (int kk = 0; kk < K; kk += CK) {
        int kc = min(CK, K - kk);
        __syncthreads();
        if (mode == 0) {
            for (int idx = t; idx < kc * H_N; idx += 256)
                Ws[idx] = W[(size_t)a * K * H_N + (size_t)kk * H_N + idx];
        } else {
            for (int idx = t; idx < kc * H_N; idx += 256) {
                int k = idx >> 7, c = idx & 127;
                Ws[idx] = W[((c >> 5) * H_N + kk + k) * D_N + (c & 31)];
            }
        }
        __syncthreads();
        for (int k = 0; k < kc; ++k) {
            float4 w4 = *(const float4*)&Ws[k * H_N + tx * 4];
#pragma unroll
            for (int j = 0; j < 8; ++j) {
                float xv = xs[(ty + 8 * j) * K + kk + k];
                acc[j][0] = fmaf(xv, w4.x, acc[j][0]);
                acc[j][1] = fmaf(xv, w4.y, acc[j][1]);
                acc[j][2] = fmaf(xv, w4.z, acc[j][2]);
                acc[j][3] = fmaf(xv, w4.w, acc[j][3]);
            }
        }
    }

    float4 bvv = {0.f, 0.f, 0.f, 0.f};
    if (bias) {
        const float* bp = bias + (bias_per_agent ? a * H_N : 0) + tx * 4;
        bvv = *(const float4*)bp;
    }
#pragma unroll
    for (int j = 0; j < 8; ++j) {
        float4 o;
        o.x = acc[j][0] + bvv.x;
        o.y = acc[j][1] + bvv.y;
        o.z = acc[j][2] + bvv.z;
        o.w = acc[j][3] + bvv.w;
        if (do_act) {
            o.x = o.x > 0.f ? o.x : 0.01f * o.x;
            o.y = o.y > 0.f ? o.y : 0.01f * o.y;
            o.z = o.z > 0.f ? o.z : 0.01f * o.z;
            o.w = o.w > 0.f ? o.w : 0.01f * o.w;
        }
        *(float4*)&out[((size_t)a * Bc + b0 + ty + 8 * j) * H_N + tx * 4] = o;
    }
}

// Attention across agents: block = 4 batch elems (slice-local), all bufs slice-local.
__global__ __launch_bounds__(256) void k_attn(const float* __restrict__ keys,
                                              const float* __restrict__ sel,
                                              const float* __restrict__ vals,
                                              int Bc,
                                              float* __restrict__ other) {
    __shared__ float ks[4 * 16 * H_N];  // 32 KB
    __shared__ float vs[4 * 16 * H_N];  // 32 KB
    int b0 = blockIdx.x * 4;
    int t = threadIdx.x;
    for (int idx4 = t; idx4 < 4 * 16 * 32; idx4 += 256) {
        int bsub = idx4 >> 9;
        int ag = (idx4 >> 5) & 15;
        int f4 = idx4 & 31;
        size_t g = ((size_t)ag * Bc + b0 + bsub) * H_N + f4 * 4;
        int l = (bsub * 16 + ag) * H_N + f4 * 4;
        *(float4*)&ks[l] = *(const float4*)&keys[g];
        *(float4*)&vs[l] = *(const float4*)&vals[g];
    }
    __syncthreads();
    int bsub = t >> 6;
    int row = t & 63;
    int n = row >> 4, i = row & 15;
    int b = b0 + bsub;

    float4 s[8];
    const float* sp = &sel[((size_t)i * Bc + b) * H_N + n * D_N];
#pragma unroll
    for (int q = 0; q < 8; ++q) s[q] = *(const float4*)&sp[q * 4];

    int base = bsub * 16 * H_N + n * D_N;
    float lg[16];
#pragma unroll
    for (int j = 0; j < 16; ++j) {
        const float* kp = &ks[base + j * H_N];
        float d = 0.f;
#pragma unroll
        for (int q = 0; q < 8; ++q) {
            float4 kv = *(const float4*)&kp[q * 4];
            d = fmaf(s[q].x, kv.x, d);
            d = fmaf(s[q].y, kv.y, d);
            d = fmaf(s[q].z, kv.z, d);
            d = fmaf(s[q].w, kv.w, d);
        }
        lg[j] = d * 0.17677669529663687f;  // 1/sqrt(32)
    }
    lg[i] = NEGV;
    float m = lg[0];
#pragma unroll
    for (int j = 1; j < 16; ++j) m = fmaxf(m, lg[j]);
    float sum = 0.f;
#pragma unroll
    for (int j = 0; j < 16; ++j) {
        lg[j] = __expf(lg[j] - m);
        sum += lg[j];
    }
    float inv = 1.f / sum;
#pragma unroll
    for (int j = 0; j < 16; ++j) lg[j] *= inv;

    float* op = &other[((size_t)i * Bc + b) * H_N + n * D_N];
#pragma unroll
    for (int q = 0; q < 8; ++q) {
        float4 o = {0.f, 0.f, 0.f, 0.f};
#pragma unroll
        for (int j = 0; j < 16; ++j) {
            const float4 vv = *(const float4*)&vs[base + j * H_N + q * 4];
            o.x = fmaf(lg[j], vv.x, o.x);
            o.y = fmaf(lg[j], vv.y, o.y);
            o.z = fmaf(lg[j], vv.z, o.z);
            o.w = fmaf(lg[j], vv.w, o.w);
        }
        *(float4*)&op[q * 4] = o;
    }
}

// Critic: h = lrelu([se|other] @ Wc1 + bc1); q = (h @ Wc2 + bc2)[argmax(actions)]
// se/other slice-local; actions/out global (offset b0g).
__global__ __launch_bounds__(256) void k_critic(
    const float* __restrict__ se, const float* __restrict__ other,
    const float* __restrict__ actions,
    const float* __restrict__ Wc1, const float* __restrict__ bc1,
    const float* __restrict__ Wc2, const float* __restrict__ bc2,
    int b0g, int Bc,
    float* __restrict__ out) {
    __shared__ float smem[64 * 64 + 64 * 128];  // 48 KB; xs|Ws, reused as hs
    float* xs = smem;             // [64][64]
    float* Ws = smem + 64 * 64;   // [64][128]
    float* hs = smem;             // [64][129] (8256 <= 12288)
    int a = blockIdx.y;
    int b0 = blockIdx.x * 64;   // slice-local
    int t = threadIdx.x;
    int tx = t & 31, ty = t >> 5;

    float acc[8][4];
    {
        float4 b4 = *(const float4*)&bc1[a * H_N + tx * 4];
#pragma unroll
        for (int j = 0; j < 8; ++j) {
            acc[j][0] = b4.x; acc[j][1] = b4.y; acc[j][2] = b4.z; acc[j][3] = b4.w;
        }
    }
    for (int kk = 0; kk < 2 * H_N; kk += 64) {
        __syncthreads();
        for (int idx = t; idx < 64 * 64; idx += 256) {
            int r = idx >> 6, k = idx & 63;
            int kg = kk + k;
            size_t row = (size_t)a * Bc + b0 + r;
            xs[idx] = (kg < H_N) ? se[row * H_N + kg] : other[row * H_N + kg - H_N];
        }
        for (int idx = t; idx < 64 * 128; idx += 256)
            Ws[idx] = Wc1[(size_t)a * 2 * H_N * H_N + (size_t)kk * H_N + idx];
        __syncthreads();
        for (int k = 0; k < 64; ++k) {
            float4 w4 = *(const float4*)&Ws[k * H_N + tx * 4];
#pragma unroll
            for (int j = 0; j < 8; ++j) {
                float xv = xs[(ty + 8 * j) * 64 + k];
                acc[j][0] = fmaf(xv, w4.x, acc[j][0]);
                acc[j][1] = fmaf(xv, w4.y, acc[j][1]);
                acc[j][2] = fmaf(xv, w4.z, acc[j][2]);
                acc[j][3] = fmaf(xv, w4.w, acc[j][3]);
            }
        }
    }
    __syncthreads();  // done reading xs/Ws before hs overwrite
#pragma unroll
    for (int j = 0; j < 8; ++j) {
        int r = ty + 8 * j;
#pragma unroll
        for (int c = 0; c < 4; ++c) {
            float v = acc[j][c];
            v = v > 0.f ? v : 0.01f * v;
            hs[r * 129 + tx * 4 + c] = v;
        }
    }
    __syncthreads();
    if (t < 64) {
        size_t bg = (size_t)a * B_N + b0g + b0 + t;  // global row
        const float* ap = &actions[bg * ACT_N];
        float bestv = ap[0];
        int bi = 0;
        for (int o2 = 1; o2 < ACT_N; ++o2) {
            float v = ap[o2];
            if (v > bestv) { bestv = v; bi = o2; }
        }
        float q = bc2[a * ACT_N + bi];
        const float* w2 = &Wc2[(size_t)a * H_N * ACT_N + bi];
        const float* hp = &hs[t * 129];
        for (int h = 0; h < H_N; ++h) q = fmaf(hp[h], w2[h * ACT_N], q);
        out[bg] = q;
    }
}

extern "C" void kernel_launch(void* const* d_in, const int* in_sizes, int n_in,
                              void* d_out, int out_size, void* d_ws, size_t ws_size,
                              hipStream_t stream) {
    const float* obs     = (const float*)d_in[0];
    const float* actions = (const float*)d_in[1];
    const float* W_sa    = (const float*)d_in[2];
    const float* b_sa    = (const float*)d_in[3];
    const float* W_s     = (const float*)d_in[4];
    const float* b_s     = (const float*)d_in[5];
    const float* Wk      = (const float*)d_in[6];
    const float* Wsel    = (const float*)d_in[7];
    const float* Wv      = (const float*)d_in[8];
    const float* bv      = (const float*)d_in[9];
    const float* Wc1     = (const float*)d_in[10];
    const float* bc1     = (const float*)d_in[11];
    const float* Wc2     = (const float*)d_in[12];
    const float* bc2     = (const float*)d_in[13];
    float* out = (float*)d_out;
    float* ws = (float*)d_ws;

    // Pick the largest batch-slice Bc whose 5 fp32 buffers fit in ws_size.
    size_t ws_floats = ws_size / 4;
    int Bc = B_N;
    while (Bc > 256 &&
           (size_t)4608 + 5ull * A_N * (size_t)Bc * H_N > ws_floats)
        Bc >>= 1;

    float* gsum = ws;            // A*IN
    float* gsq  = ws + 2304;     // A*IN
    const size_t SZ = (size_t)A_N * Bc * H_N;
    float* sa   = ws + 4608;
    float* se   = sa + SZ;
    float* keys = se + SZ;
    float* vals = keys + SZ;
    float* sel  = vals + SZ;
    float* other = sa;  // sa is dead once keys/vals are computed

    // BN stats over the FULL batch (once).
    k_zero<<<dim3(18), dim3(256), 0, stream>>>(gsum, 2 * A_N * IN_N);
    k_stats<<<dim3(A_N * 8), dim3(256), 0, stream>>>(obs, actions, gsum, gsq);
    k_finalize<<<dim3(9), dim3(256), 0, stream>>>(gsum, gsq);

    for (int b0g = 0; b0g < B_N; b0g += Bc) {
        dim3 gg(Bc / 64, A_N);
        // sa = lrelu(bn(inp) @ W_sa + b_sa)
        k_gemm<<<gg, 256, 0, stream>>>(obs, actions, nullptr, gsum, gsq, W_sa,
                                       b_sa, 1, IN_N, 0, 1, b0g, Bc, sa);
        // se = lrelu(bn(obs) @ W_s + b_s)
        k_gemm<<<gg, 256, 0, stream>>>(obs, actions, nullptr, gsum, gsq, W_s,
                                       b_s, 1, O_N, 0, 1, b0g, Bc, se);
        // keys = sa @ Wk
        k_gemm<<<gg, 256, 0, stream>>>(nullptr, nullptr, sa, nullptr, nullptr,
                                       Wk, nullptr, 0, H_N, 1, 0, b0g, Bc, keys);
        // vals = lrelu(sa @ Wv + bv)
        k_gemm<<<gg, 256, 0, stream>>>(nullptr, nullptr, sa, nullptr, nullptr,
                                       Wv, bv, 0, H_N, 1, 1, b0g, Bc, vals);
        // sel = se @ Wsel
        k_gemm<<<gg, 256, 0, stream>>>(nullptr, nullptr, se, nullptr, nullptr,
                                       Wsel, nullptr, 0, H_N, 1, 0, b0g, Bc, sel);

        k_attn<<<dim3(Bc / 4), dim3(256), 0, stream>>>(keys, sel, vals, Bc, other);

        k_critic<<<gg, 256, 0, stream>>>(se, other, actions, Wc1, bc1, Wc2, bc2,
                                         b0g, Bc, out);
    }
}

// Round 3
// 598.961 us; speedup vs baseline: 1.8908x; 1.8908x over previous
//
#include <hip/hip_runtime.h>
#include <hip/hip_bf16.h>

#define A_N 16
#define B_N 8192
#define O_N 128
#define ACT_N 16
#define H_N 128
#define NH_N 4
#define D_N 32
#define IN_N 144
#define NEGV -1e9f

typedef __attribute__((ext_vector_type(8))) short short8;
typedef __attribute__((ext_vector_type(4))) float floatx4;

// ---- bf16 helpers (RNE) -------------------------------------------------
static __device__ inline unsigned short f2bf(float f) {
    union { float f; unsigned u; } x{f};
    unsigned u = x.u + 0x7FFFu + ((x.u >> 16) & 1u);
    return (unsigned short)(u >> 16);
}
static __device__ inline unsigned pack_bf2(float a, float b) {
    union { float f; unsigned u; } xa{a}, xb{b};
    unsigned ua = xa.u + 0x7FFFu + ((xa.u >> 16) & 1u);
    unsigned ub = xb.u + 0x7FFFu + ((xb.u >> 16) & 1u);
    return (ua >> 16) | (ub & 0xFFFF0000u);
}
static __device__ inline float bf2f(unsigned short h) {
    union { unsigned u; float f; } x;
    x.u = ((unsigned)h) << 16;
    return x.f;
}
static __device__ inline short8 ld_frag(const unsigned* p) {
    union { unsigned u[4]; short8 v; } x;
    uint2 lo = *(const uint2*)p;
    uint2 hi = *(const uint2*)(p + 2);
    x.u[0] = lo.x; x.u[1] = lo.y; x.u[2] = hi.x; x.u[3] = hi.y;
    return x.v;
}

// ---- misc small kernels -------------------------------------------------
__global__ __launch_bounds__(256) void k_zero(float* p, int n) {
    int i = blockIdx.x * 256 + threadIdx.x;
    if (i < n) p[i] = 0.f;
}

// Fast BN stats: grid = A*32 blocks, each covers 256 rows. Register
// accumulation (one feature column per thread), no LDS atomics on hot path.
__global__ __launch_bounds__(256) void k_stats(const float* __restrict__ obs,
                                               const float* __restrict__ act,
                                               float* __restrict__ gsum,
                                               float* __restrict__ gsq) {
    __shared__ float ssum[IN_N];
    __shared__ float ssq[IN_N];
    int a = blockIdx.x >> 5;
    int r0 = (blockIdx.x & 31) * 256;
    int t = threadIdx.x;
    if (t < IN_N) { ssum[t] = 0.f; ssq[t] = 0.f; }
    __syncthreads();
    if (t < 128) {
        const float* p = obs + ((size_t)a * B_N + r0) * O_N + t;
        float s = 0.f, q = 0.f;
#pragma unroll 4
        for (int r = 0; r < 256; ++r) {
            float v = p[(size_t)r * O_N];
            s += v; q += v * v;
        }
        ssum[t] = s; ssq[t] = q;
    } else {
        int tt = t - 128;
        int f = tt & 15, rg = tt >> 4;  // 8 row-groups
        const float* p = act + ((size_t)a * B_N + r0 + rg) * ACT_N + f;
        float s = 0.f, q = 0.f;
#pragma unroll 4
        for (int i = 0; i < 32; ++i) {
            float v = p[(size_t)i * 8 * ACT_N];
            s += v; q += v * v;
        }
        atomicAdd(&ssum[O_N + f], s);
        atomicAdd(&ssq[O_N + f], q);
    }
    __syncthreads();
    if (t < IN_N) {
        atomicAdd(&gsum[a * IN_N + t], ssum[t]);
        atomicAdd(&gsq[a * IN_N + t], ssq[t]);
    }
}

__global__ __launch_bounds__(256) void k_finalize(float* gsum, float* gsq) {
    int i = blockIdx.x * 256 + threadIdx.x;
    if (i < A_N * IN_N) {
        const float invB = 1.f / (float)B_N;
        float m = gsum[i] * invB;
        float v = fmaxf(gsq[i] * invB - m * m, 0.f);
        gsum[i] = m;
        gsq[i] = rsqrtf(v + 1e-5f);
    }
}

// ---- weight prep: fp32 -> bf16, transposed to [n][k/2] packed uints -----
// wt_l1: [a][256][96]  cols 0-127: W_sa (K=144, zero-pad to 192); 128-255: W_s
// wt_p1: [256][64]     cols 0-127: Wk;  128-255: Wv  (K=128)
// wt_p2: [128][64]     Wsel (K=128)
// wt_cr: [a][128][128] Wc1  (K=256)
#define L1E 393216
#define P1E 409600
#define P2E 417792
#define CRE 679936
__global__ __launch_bounds__(256) void k_wprep(
    const float* __restrict__ W_sa, const float* __restrict__ W_s,
    const float* __restrict__ Wk, const float* __restrict__ Wsel,
    const float* __restrict__ Wv, const float* __restrict__ Wc1,
    unsigned* __restrict__ wt_l1, unsigned* __restrict__ wt_p1,
    unsigned* __restrict__ wt_p2, unsigned* __restrict__ wt_cr) {
    int idx = blockIdx.x * 256 + threadIdx.x;
    if (idx < L1E) {
        int a = idx / 24576, rem = idx % 24576;
        int n = rem & 255, kp = rem >> 8;  // kp 0..95
        int k0 = 2 * kp, k1 = k0 + 1;
        float v0, v1;
        if (n < 128) {
            v0 = (k0 < IN_N) ? W_sa[((size_t)a * IN_N + k0) * H_N + n] : 0.f;
            v1 = (k1 < IN_N) ? W_sa[((size_t)a * IN_N + k1) * H_N + n] : 0.f;
        } else {
            int m = n - 128;
            v0 = (k0 < O_N) ? W_s[((size_t)a * O_N + k0) * H_N + m] : 0.f;
            v1 = (k1 < O_N) ? W_s[((size_t)a * O_N + k1) * H_N + m] : 0.f;
        }
        wt_l1[(size_t)a * 24576 + n * 96 + kp] = pack_bf2(v0, v1);
    } else if (idx < P1E) {
        int i2 = idx - L1E;
        int n = i2 & 255, kp = i2 >> 8;  // kp 0..63
        int k0 = 2 * kp;
        float v0, v1;
        if (n < 128) {
            const float* w = Wk + ((size_t)(n >> 5) * H_N) * D_N + (n & 31);
            v0 = w[(size_t)k0 * D_N]; v1 = w[(size_t)(k0 + 1) * D_N];
        } else {
            int m = n - 128;
            const float* w = Wv + ((size_t)(m >> 5) * H_N) * D_N + (m & 31);
            v0 = w[(size_t)k0 * D_N]; v1 = w[(size_t)(k0 + 1) * D_N];
        }
        wt_p1[n * 64 + kp] = pack_bf2(v0, v1);
    } else if (idx < P2E) {
        int i3 = idx - P1E;
        int n = i3 & 127, kp = i3 >> 7;
        int k0 = 2 * kp;
        const float* w = Wsel + ((size_t)(n >> 5) * H_N) * D_N + (n & 31);
        wt_p2[n * 64 + kp] = pack_bf2(w[(size_t)k0 * D_N], w[(size_t)(k0 + 1) * D_N]);
    } else if (idx < CRE) {
        int i4 = idx - P2E;
        int a = i4 >> 14, r = i4 & 16383;
        int n = r & 127, kp = r >> 7;  // kp 0..127
        int k0 = 2 * kp;
        const float* w = Wc1 + (size_t)a * 256 * H_N + n;
        wt_cr[(size_t)a * 16384 + n * 128 + kp] =
            pack_bf2(w[(size_t)k0 * H_N], w[(size_t)(k0 + 1) * H_N]);
    }
}

// ---- unified MFMA GEMM --------------------------------------------------
// Block: 128(batch rows) x NT(cols), 256 thr = 4 waves in 2x2 (64r x NT/2 c).
// MFMA 16x16x32 bf16. LDS: Xs[128][34] + Ws[NT][34] packed-bf16 uints.
// MODE 0 (L1): X = BN(concat(obs,act)) fp32->bf16; out sa(bf16), cin[:,0:128](bf16)
// MODE 1 (P1): X = sa; out keys(fp32), vals(fp32, bias+lrelu)
// MODE 2 (P2): X = cin[:,0:128]; out sel(fp32)
// MODE 3 (CR): X = cin; h->LDS bf16; q = h . Wc2[:,argmax(actions)] + bc2
template<int MODE, int NT, int KCH, int KSTOP, int KT2>
__global__ __launch_bounds__(256) void k_mfma(
    const float* __restrict__ obs, const float* __restrict__ act,
    const float* __restrict__ mean, const float* __restrict__ rstd,
    const unsigned* __restrict__ Xsrc, int xsU,
    const unsigned* __restrict__ Wt,
    const float* __restrict__ bias0, const float* __restrict__ bias1,
    unsigned short* __restrict__ bout0, unsigned short* __restrict__ bout1,
    float* __restrict__ fout0, float* __restrict__ fout1,
    const float* __restrict__ actions, const float* __restrict__ Wc2,
    const float* __restrict__ bc2, float* __restrict__ qout,
    int b0g, int Bc) {
    constexpr int NTILES = NT / 32;
    __shared__ unsigned smem[(128 + NT) * 34];
    unsigned* Xs = smem;
    unsigned* Ws = smem + 128 * 34;

    int a = blockIdx.y;
    int b0 = blockIdx.x * 128;  // slice-local row base
    int t = threadIdx.x;
    int wid = t >> 6, lane = t & 63, lm = lane & 15, lq = lane >> 4;
    int wrow = (wid & 1) * 64;
    int wcol = (wid >> 1) * (NT / 2);

    floatx4 acc[4][NTILES];
#pragma unroll
    for (int mt = 0; mt < 4; ++mt)
#pragma unroll
        for (int nt = 0; nt < NTILES; ++nt)
#pragma unroll
            for (int e = 0; e < 4; ++e) acc[mt][nt][e] = 0.f;

    const unsigned* WtA = Wt;
    if constexpr (MODE == 0) WtA = Wt + (size_t)a * 256 * KT2;
    if constexpr (MODE == 3) WtA = Wt + (size_t)a * 128 * KT2;

    for (int c = 0; c < KCH; ++c) {
        int kk = c * 64;
        __syncthreads();
        if constexpr (MODE == 0) {
            for (int idx = t; idx < 128 * 32; idx += 256) {
                int r = idx >> 5, kp = idx & 31;
                int k = kk + 2 * kp;
                float v0 = 0.f, v1 = 0.f;
                if (k < IN_N) {
                    size_t grow = (size_t)a * B_N + b0g + b0 + r;
                    float x0 = (k < O_N) ? obs[grow * O_N + k]
                                         : act[grow * ACT_N + k - O_N];
                    float x1 = (k + 1 < O_N) ? obs[grow * O_N + k + 1]
                                             : act[grow * ACT_N + k + 1 - O_N];
                    v0 = (x0 - mean[a * IN_N + k]) * rstd[a * IN_N + k];
                    v1 = (x1 - mean[a * IN_N + k + 1]) * rstd[a * IN_N + k + 1];
                }
                Xs[r * 34 + kp] = pack_bf2(v0, v1);
            }
        } else {
            for (int idx = t; idx < 128 * 32; idx += 256) {
                int r = idx >> 5, kp = idx & 31;
                Xs[r * 34 + kp] =
                    Xsrc[((size_t)a * Bc + b0 + r) * xsU + (kk >> 1) + kp];
            }
        }
        for (int idx = t; idx < NT * 32; idx += 256) {
            int n = idx >> 5, kp = idx & 31;
            Ws[n * 34 + kp] = WtA[(size_t)n * KT2 + (kk >> 1) + kp];
        }
        __syncthreads();
#pragma unroll
        for (int s = 0; s < 2; ++s) {
            if (kk + s * 32 >= KSTOP) break;
            short8 afr[4];
#pragma unroll
            for (int mt = 0; mt < 4; ++mt) {
                int row = wrow + mt * 16 + lm;
                afr[mt] = ld_frag(&Xs[row * 34 + s * 16 + lq * 4]);
            }
#pragma unroll
            for (int nt = 0; nt < NTILES; ++nt) {
                int col = wcol + nt * 16 + lm;
                short8 bfr = ld_frag(&Ws[col * 34 + s * 16 + lq * 4]);
#pragma unroll
                for (int mt = 0; mt < 4; ++mt)
                    acc[mt][nt] = __builtin_amdgcn_mfma_f32_16x16x32_bf16(
                        afr[mt], bfr, acc[mt][nt], 0, 0, 0);
            }
        }
    }

    if constexpr (MODE == 3) {
        __syncthreads();  // smem reuse for h
        unsigned short* hbuf = (unsigned short*)smem;  // [128][132]
#pragma unroll
        for (int mt = 0; mt < 4; ++mt)
#pragma unroll
            for (int nt = 0; nt < NTILES; ++nt)
#pragma unroll
                for (int r = 0; r < 4; ++r) {
                    int row = wrow + mt * 16 + lq * 4 + r;
                    int col = wcol + nt * 16 + lm;
                    float v = acc[mt][nt][r] + bias0[a * H_N + col];
                    v = v > 0.f ? v : 0.01f * v;
                    hbuf[row * 132 + col] = f2bf(v);
                }
        __syncthreads();
        if (t < 128) {
            size_t arow = (size_t)a * B_N + b0g + b0 + t;
            const float* ap = &actions[arow * ACT_N];
            float bestv = ap[0];
            int bi = 0;
            for (int o = 1; o < ACT_N; ++o) {
                float v = ap[o];
                if (v > bestv) { bestv = v; bi = o; }
            }
            float q = bc2[a * ACT_N + bi];
            const float* w2 = &Wc2[((size_t)a * H_N) * ACT_N + bi];
            const unsigned short* hp = &hbuf[t * 132];
#pragma unroll 8
            for (int h = 0; h < H_N; ++h)
                q = fmaf(bf2f(hp[h]), w2[(size_t)h * ACT_N], q);
            qout[arow] = q;
        }
        return;
    }

#pragma unroll
    for (int mt = 0; mt < 4; ++mt)
#pragma unroll
        for (int nt = 0; nt < NTILES; ++nt)
#pragma unroll
            for (int r = 0; r < 4; ++r) {
                int row = b0 + wrow + mt * 16 + lq * 4 + r;  // slice-local
                int col = wcol + nt * 16 + lm;
                float v = acc[mt][nt][r];
                size_t rbase = (size_t)a * Bc + row;
                if constexpr (MODE == 0) {
                    if (col < 128) {
                        v += bias0[a * H_N + col];
                        v = v > 0.f ? v : 0.01f * v;
                        bout0[rbase * 128 + col] = f2bf(v);  // sa
                    } else {
                        v += bias1[a * H_N + col - 128];
                        v = v > 0.f ? v : 0.01f * v;
                        bout1[rbase * 256 + (col - 128)] = f2bf(v);  // cin: se
                    }
                } else if constexpr (MODE == 1) {
                    if (col < 128) {
                        fout0[rbase * 128 + col] = v;  // keys
                    } else {
                        v += bias0[col - 128];  // bv
                        v = v > 0.f ? v : 0.01f * v;
                        fout1[rbase * 128 + (col - 128)] = v;  // vals
                    }
                } else {  // MODE 2
                    fout0[rbase * 128 + col] = v;  // sel
                }
            }
}

// ---- attention (fp32 math, bf16 output into cin[:,128:]) ----------------
__global__ __launch_bounds__(256) void k_attn(const float* __restrict__ keys,
                                              const float* __restrict__ sel,
                                              const float* __restrict__ vals,
                                              unsigned short* __restrict__ cin,
                                              int Bc) {
    __shared__ float ks[4 * 16 * H_N];
    __shared__ float vs[4 * 16 * H_N];
    int b0 = blockIdx.x * 4;
    int t = threadIdx.x;
    for (int idx4 = t; idx4 < 4 * 16 * 32; idx4 += 256) {
        int bsub = idx4 >> 9;
        int ag = (idx4 >> 5) & 15;
        int f4 = idx4 & 31;
        size_t g = ((size_t)ag * Bc + b0 + bsub) * H_N + f4 * 4;
        int l = (bsub * 16 + ag) * H_N + f4 * 4;
        *(float4*)&ks[l] = *(const float4*)&keys[g];
        *(float4*)&vs[l] = *(const float4*)&vals[g];
    }
    __syncthreads();
    int bsub = t >> 6;
    int row = t & 63;
    int n = row >> 4, i = row & 15;
    int b = b0 + bsub;

    float4 s[8];
    const float* sp = &sel[((size_t)i * Bc + b) * H_N + n * D_N];
#pragma unroll
    for (int q = 0; q < 8; ++q) s[q] = *(const float4*)&sp[q * 4];

    int base = bsub * 16 * H_N + n * D_N;
    float lg[16];
#pragma unroll
    for (int j = 0; j < 16; ++j) {
        const float* kp = &ks[base + j * H_N];
        float d = 0.f;
#pragma unroll
        for (int q = 0; q < 8; ++q) {
            float4 kv = *(const float4*)&kp[q * 4];
            d = fmaf(s[q].x, kv.x, d);
            d = fmaf(s[q].y, kv.y, d);
            d = fmaf(s[q].z, kv.z, d);
            d = fmaf(s[q].w, kv.w, d);
        }
        lg[j] = d * 0.17677669529663687f;
    }
    lg[i] = NEGV;
    float m = lg[0];
#pragma unroll
    for (int j = 1; j < 16; ++j) m = fmaxf(m, lg[j]);
    float sum = 0.f;
#pragma unroll
    for (int j = 0; j < 16; ++j) {
        lg[j] = __expf(lg[j] - m);
        sum += lg[j];
    }
    float inv = 1.f / sum;
#pragma unroll
    for (int j = 0; j < 16; ++j) lg[j] *= inv;

    unsigned short* op = &cin[((size_t)i * Bc + b) * 256 + 128 + n * D_N];
#pragma unroll
    for (int q = 0; q < 8; ++q) {
        float4 o = {0.f, 0.f, 0.f, 0.f};
#pragma unroll
        for (int j = 0; j < 16; ++j) {
            const float4 vv = *(const float4*)&vs[base + j * H_N + q * 4];
            o.x = fmaf(lg[j], vv.x, o.x);
            o.y = fmaf(lg[j], vv.y, o.y);
            o.z = fmaf(lg[j], vv.z, o.z);
            o.w = fmaf(lg[j], vv.w, o.w);
        }
        ushort4 o4;
        o4.x = f2bf(o.x); o4.y = f2bf(o.y); o4.z = f2bf(o.z); o4.w = f2bf(o.w);
        *(ushort4*)&op[q * 4] = o4;
    }
}

extern "C" void kernel_launch(void* const* d_in, const int* in_sizes, int n_in,
                              void* d_out, int out_size, void* d_ws, size_t ws_size,
                              hipStream_t stream) {
    const float* obs     = (const float*)d_in[0];
    const float* actions = (const float*)d_in[1];
    const float* W_sa    = (const float*)d_in[2];
    const float* b_sa    = (const float*)d_in[3];
    const float* W_s     = (const float*)d_in[4];
    const float* b_s     = (const float*)d_in[5];
    const float* Wk      = (const float*)d_in[6];
    const float* Wsel    = (const float*)d_in[7];
    const float* Wv      = (const float*)d_in[8];
    const float* bv      = (const float*)d_in[9];
    const float* Wc1     = (const float*)d_in[10];
    const float* bc1     = (const float*)d_in[11];
    const float* Wc2     = (const float*)d_in[12];
    const float* bc2     = (const float*)d_in[13];
    float* out = (float*)d_out;
    char* ws = (char*)d_ws;

    // fixed region
    size_t o = 0;
    float* gsum = (float*)(ws + o); o += 2304 * 4;
    float* gsq  = (float*)(ws + o); o += 2304 * 4;
    unsigned* wt_l1 = (unsigned*)(ws + o); o += (size_t)393216 * 4;
    unsigned* wt_p1 = (unsigned*)(ws + o); o += (size_t)16384 * 4;
    unsigned* wt_p2 = (unsigned*)(ws + o); o += (size_t)8192 * 4;
    unsigned* wt_cr = (unsigned*)(ws + o); o += (size_t)262144 * 4;
    size_t fixed = o;  // 2738176 B

    int Bc = B_N;
    while (Bc > 128 && fixed + 36864ull * Bc > ws_size) Bc >>= 1;

    unsigned short* sa_us  = (unsigned short*)(ws + o); o += (size_t)16 * Bc * 128 * 2;
    unsigned short* cin_us = (unsigned short*)(ws + o); o += (size_t)16 * Bc * 256 * 2;
    float* keys = (float*)(ws + o); o += (size_t)16 * Bc * 128 * 4;
    float* vals = (float*)(ws + o); o += (size_t)16 * Bc * 128 * 4;
    float* sel  = (float*)(ws + o); o += (size_t)16 * Bc * 128 * 4;

    k_zero<<<dim3(18), 256, 0, stream>>>(gsum, 2 * A_N * IN_N);
    k_stats<<<dim3(A_N * 32), 256, 0, stream>>>(obs, actions, gsum, gsq);
    k_finalize<<<dim3(9), 256, 0, stream>>>(gsum, gsq);
    k_wprep<<<dim3(CRE / 256), 256, 0, stream>>>(W_sa, W_s, Wk, Wsel, Wv, Wc1,
                                                 wt_l1, wt_p1, wt_p2, wt_cr);

    for (int b0g = 0; b0g < B_N; b0g += Bc) {
        dim3 gg(Bc / 128, A_N);
        // L1: sa | se
        k_mfma<0, 256, 3, 160, 96><<<gg, 256, 0, stream>>>(
            obs, actions, gsum, gsq, nullptr, 0, wt_l1, b_sa, b_s,
            sa_us, cin_us, nullptr, nullptr, nullptr, nullptr, nullptr, nullptr,
            b0g, Bc);
        // P1: keys | vals
        k_mfma<1, 256, 2, 128, 64><<<gg, 256, 0, stream>>>(
            nullptr, nullptr, nullptr, nullptr, (const unsigned*)sa_us, 64,
            wt_p1, bv, nullptr, nullptr, nullptr, keys, vals,
            nullptr, nullptr, nullptr, nullptr, b0g, Bc);
        // P2: sel
        k_mfma<2, 128, 2, 128, 64><<<gg, 256, 0, stream>>>(
            nullptr, nullptr, nullptr, nullptr, (const unsigned*)cin_us, 128,
            wt_p2, nullptr, nullptr, nullptr, nullptr, sel, nullptr,
            nullptr, nullptr, nullptr, nullptr, b0g, Bc);
        // attention -> cin[:,128:]
        k_attn<<<dim3(Bc / 4), 256, 0, stream>>>(keys, sel, vals, cin_us, Bc);
        // critic -> q
        k_mfma<3, 128, 4, 256, 128><<<gg, 256, 0, stream>>>(
            nullptr, nullptr, nullptr, nullptr, (const unsigned*)cin_us, 128,
            wt_cr, bc1, nullptr, nullptr, nullptr, nullptr, nullptr,
            actions, Wc2, bc2, out, b0g, Bc);
    }
}

// Round 4
// 498.072 us; speedup vs baseline: 2.2738x; 1.2026x over previous
//
#include <hip/hip_runtime.h>
#include <hip/hip_bf16.h>

#define A_N 16
#define B_N 8192
#define O_N 128
#define ACT_N 16
#define H_N 128
#define NH_N 4
#define D_N 32
#define IN_N 144
#define NEGV -1e9f

typedef __attribute__((ext_vector_type(8))) short short8;
typedef __attribute__((ext_vector_type(4))) float floatx4;

// ---- bf16 helpers (RNE) -------------------------------------------------
static __device__ inline unsigned short f2bf(float f) {
    union { float f; unsigned u; } x{f};
    unsigned u = x.u + 0x7FFFu + ((x.u >> 16) & 1u);
    return (unsigned short)(u >> 16);
}
static __device__ inline unsigned pack_bf2(float a, float b) {
    union { float f; unsigned u; } xa{a}, xb{b};
    unsigned ua = xa.u + 0x7FFFu + ((xa.u >> 16) & 1u);
    unsigned ub = xb.u + 0x7FFFu + ((xb.u >> 16) & 1u);
    return (ua >> 16) | (ub & 0xFFFF0000u);
}
static __device__ inline float bf2f(unsigned short h) {
    union { unsigned u; float f; } x;
    x.u = ((unsigned)h) << 16;
    return x.f;
}
static __device__ inline float bflo(unsigned u) {
    union { unsigned u; float f; } x; x.u = u << 16; return x.f;
}
static __device__ inline float bfhi(unsigned u) {
    union { unsigned u; float f; } x; x.u = u & 0xFFFF0000u; return x.f;
}
static __device__ inline short8 ld_frag(const unsigned* p) {
    union { unsigned u[4]; short8 v; } x;
    uint2 lo = *(const uint2*)p;
    uint2 hi = *(const uint2*)(p + 2);
    x.u[0] = lo.x; x.u[1] = lo.y; x.u[2] = hi.x; x.u[3] = hi.y;
    return x.v;
}

// ---- misc small kernels -------------------------------------------------
__global__ __launch_bounds__(256) void k_zero(float* p, int n) {
    int i = blockIdx.x * 256 + threadIdx.x;
    if (i < n) p[i] = 0.f;
}

__global__ __launch_bounds__(256) void k_stats(const float* __restrict__ obs,
                                               const float* __restrict__ act,
                                               float* __restrict__ gsum,
                                               float* __restrict__ gsq) {
    __shared__ float ssum[IN_N];
    __shared__ float ssq[IN_N];
    int a = blockIdx.x >> 5;
    int r0 = (blockIdx.x & 31) * 256;
    int t = threadIdx.x;
    if (t < IN_N) { ssum[t] = 0.f; ssq[t] = 0.f; }
    __syncthreads();
    if (t < 128) {
        const float* p = obs + ((size_t)a * B_N + r0) * O_N + t;
        float s = 0.f, q = 0.f;
#pragma unroll 4
        for (int r = 0; r < 256; ++r) {
            float v = p[(size_t)r * O_N];
            s += v; q += v * v;
        }
        ssum[t] = s; ssq[t] = q;
    } else {
        int tt = t - 128;
        int f = tt & 15, rg = tt >> 4;
        const float* p = act + ((size_t)a * B_N + r0 + rg) * ACT_N + f;
        float s = 0.f, q = 0.f;
#pragma unroll 4
        for (int i = 0; i < 32; ++i) {
            float v = p[(size_t)i * 8 * ACT_N];
            s += v; q += v * v;
        }
        atomicAdd(&ssum[O_N + f], s);
        atomicAdd(&ssq[O_N + f], q);
    }
    __syncthreads();
    if (t < IN_N) {
        atomicAdd(&gsum[a * IN_N + t], ssum[t]);
        atomicAdd(&gsq[a * IN_N + t], ssq[t]);
    }
}

__global__ __launch_bounds__(256) void k_finalize(float* gsum, float* gsq) {
    int i = blockIdx.x * 256 + threadIdx.x;
    if (i < A_N * IN_N) {
        const float invB = 1.f / (float)B_N;
        float m = gsum[i] * invB;
        float v = fmaxf(gsq[i] * invB - m * m, 0.f);
        gsum[i] = m;
        gsq[i] = rsqrtf(v + 1e-5f);
    }
}

// ---- weight prep: fp32 -> bf16, transposed to [n][k/2] packed uints -----
#define L1E 393216
#define P1E 409600
#define P2E 417792
#define CRE 679936
__global__ __launch_bounds__(256) void k_wprep(
    const float* __restrict__ W_sa, const float* __restrict__ W_s,
    const float* __restrict__ Wk, const float* __restrict__ Wsel,
    const float* __restrict__ Wv, const float* __restrict__ Wc1,
    unsigned* __restrict__ wt_l1, unsigned* __restrict__ wt_p1,
    unsigned* __restrict__ wt_p2, unsigned* __restrict__ wt_cr) {
    int idx = blockIdx.x * 256 + threadIdx.x;
    if (idx < L1E) {
        int a = idx / 24576, rem = idx % 24576;
        int n = rem & 255, kp = rem >> 8;  // kp 0..95
        int k0 = 2 * kp, k1 = k0 + 1;
        float v0, v1;
        if (n < 128) {
            v0 = (k0 < IN_N) ? W_sa[((size_t)a * IN_N + k0) * H_N + n] : 0.f;
            v1 = (k1 < IN_N) ? W_sa[((size_t)a * IN_N + k1) * H_N + n] : 0.f;
        } else {
            int m = n - 128;
            v0 = (k0 < O_N) ? W_s[((size_t)a * O_N + k0) * H_N + m] : 0.f;
            v1 = (k1 < O_N) ? W_s[((size_t)a * O_N + k1) * H_N + m] : 0.f;
        }
        wt_l1[(size_t)a * 24576 + n * 96 + kp] = pack_bf2(v0, v1);
    } else if (idx < P1E) {
        int i2 = idx - L1E;
        int n = i2 & 255, kp = i2 >> 8;  // kp 0..63
        int k0 = 2 * kp;
        float v0, v1;
        if (n < 128) {
            const float* w = Wk + ((size_t)(n >> 5) * H_N) * D_N + (n & 31);
            v0 = w[(size_t)k0 * D_N]; v1 = w[(size_t)(k0 + 1) * D_N];
        } else {
            int m = n - 128;
            const float* w = Wv + ((size_t)(m >> 5) * H_N) * D_N + (m & 31);
            v0 = w[(size_t)k0 * D_N]; v1 = w[(size_t)(k0 + 1) * D_N];
        }
        wt_p1[n * 64 + kp] = pack_bf2(v0, v1);
    } else if (idx < P2E) {
        int i3 = idx - P1E;
        int n = i3 & 127, kp = i3 >> 7;
        int k0 = 2 * kp;
        const float* w = Wsel + ((size_t)(n >> 5) * H_N) * D_N + (n & 31);
        wt_p2[n * 64 + kp] = pack_bf2(w[(size_t)k0 * D_N], w[(size_t)(k0 + 1) * D_N]);
    } else if (idx < CRE) {
        int i4 = idx - P2E;
        int a = i4 >> 14, r = i4 & 16383;
        int n = r & 127, kp = r >> 7;  // kp 0..127
        int k0 = 2 * kp;
        const float* w = Wc1 + (size_t)a * 256 * H_N + n;
        wt_cr[(size_t)a * 16384 + n * 128 + kp] =
            pack_bf2(w[(size_t)k0 * H_N], w[(size_t)(k0 + 1) * H_N]);
    }
}

// ---- L1: sa|se = lrelu(BN(concat(obs,act)) @ [W_sa|W_s] + b) ------------
// 128 rows x 256 cols per block, 4 waves 2x2. Outputs bf16.
__global__ __launch_bounds__(256) void k_l1(
    const float* __restrict__ obs, const float* __restrict__ act,
    const float* __restrict__ mean, const float* __restrict__ rstd,
    const unsigned* __restrict__ wt_l1,
    const float* __restrict__ b_sa, const float* __restrict__ b_s,
    unsigned short* __restrict__ sa_us, unsigned short* __restrict__ se_us,
    int b0g, int Bc) {
    __shared__ unsigned smem[(128 + 256) * 34];
    unsigned* Xs = smem;
    unsigned* Ws = smem + 128 * 34;

    int a = blockIdx.y;
    int b0 = blockIdx.x * 128;
    int t = threadIdx.x;
    int wid = t >> 6, lane = t & 63, lm = lane & 15, lq = lane >> 4;
    int wrow = (wid & 1) * 64;
    int wcol = (wid >> 1) * 128;

    floatx4 acc[4][8];
#pragma unroll
    for (int mt = 0; mt < 4; ++mt)
#pragma unroll
        for (int nt = 0; nt < 8; ++nt)
#pragma unroll
            for (int e = 0; e < 4; ++e) acc[mt][nt][e] = 0.f;

    const unsigned* WtA = wt_l1 + (size_t)a * 24576;

    for (int c = 0; c < 3; ++c) {
        int kk = c * 64;
        __syncthreads();
        for (int idx = t; idx < 128 * 32; idx += 256) {
            int r = idx >> 5, kp = idx & 31;
            int k = kk + 2 * kp;
            float v0 = 0.f, v1 = 0.f;
            if (k < IN_N) {
                size_t grow = (size_t)a * B_N + b0g + b0 + r;
                float x0 = (k < O_N) ? obs[grow * O_N + k]
                                     : act[grow * ACT_N + k - O_N];
                float x1 = (k + 1 < O_N) ? obs[grow * O_N + k + 1]
                                         : act[grow * ACT_N + k + 1 - O_N];
                v0 = (x0 - mean[a * IN_N + k]) * rstd[a * IN_N + k];
                v1 = (x1 - mean[a * IN_N + k + 1]) * rstd[a * IN_N + k + 1];
            }
            Xs[r * 34 + kp] = pack_bf2(v0, v1);
        }
        for (int idx = t; idx < 256 * 32; idx += 256) {
            int n = idx >> 5, kp = idx & 31;
            Ws[n * 34 + kp] = WtA[(size_t)n * 96 + (kk >> 1) + kp];
        }
        __syncthreads();
#pragma unroll
        for (int s = 0; s < 2; ++s) {
            if (kk + s * 32 >= 160) break;
            short8 afr[4];
#pragma unroll
            for (int mt = 0; mt < 4; ++mt)
                afr[mt] = ld_frag(&Xs[(wrow + mt * 16 + lm) * 34 + s * 16 + lq * 4]);
#pragma unroll
            for (int nt = 0; nt < 8; ++nt) {
                short8 bfr = ld_frag(&Ws[(wcol + nt * 16 + lm) * 34 + s * 16 + lq * 4]);
#pragma unroll
                for (int mt = 0; mt < 4; ++mt)
                    acc[mt][nt] = __builtin_amdgcn_mfma_f32_16x16x32_bf16(
                        afr[mt], bfr, acc[mt][nt], 0, 0, 0);
            }
        }
    }

#pragma unroll
    for (int mt = 0; mt < 4; ++mt)
#pragma unroll
        for (int nt = 0; nt < 8; ++nt)
#pragma unroll
            for (int r = 0; r < 4; ++r) {
                int row = b0 + wrow + mt * 16 + lq * 4 + r;
                int col = wcol + nt * 16 + lm;
                float v = acc[mt][nt][r];
                size_t rbase = (size_t)a * Bc + row;
                if (col < 128) {
                    v += b_sa[a * H_N + col];
                    v = v > 0.f ? v : 0.01f * v;
                    sa_us[rbase * 128 + col] = f2bf(v);
                } else {
                    v += b_s[a * H_N + col - 128];
                    v = v > 0.f ? v : 0.01f * v;
                    se_us[rbase * 128 + (col - 128)] = f2bf(v);
                }
            }
}

// ---- fused: keys|vals|sel GEMMs (LDS-only) + attention -> other (bf16) --
// Block = 4 batch elems x 16 agents = 64 rows. Weights read from L2 as frags.
__global__ __launch_bounds__(256) void k_fused(
    const unsigned* __restrict__ sa_u, const unsigned* __restrict__ se_u,
    const unsigned* __restrict__ wt_p1, const unsigned* __restrict__ wt_p2,
    const float* __restrict__ bv, unsigned short* __restrict__ other_us,
    int Bc) {
    __shared__ unsigned Xs[64 * 65];            // 16640 B (sa, then se; sel after)
    __shared__ unsigned short keys_s[64 * 130]; // 16640 B
    __shared__ unsigned short vals_s[64 * 130]; // 16640 B
    unsigned short* sel_s = (unsigned short*)Xs;

    int bg0 = blockIdx.x * 4;
    int t = threadIdx.x;
    int wid = t >> 6, lane = t & 63, lm = lane & 15, lq = lane >> 4;
    int wrow = (wid & 1) * 32;

    // ---- load sa rows [64][64 uints] ----
    for (int idx = t; idx < 64 * 64; idx += 256) {
        int r = idx >> 6, kp = idx & 63;
        int a = r >> 2, b = bg0 + (r & 3);
        Xs[r * 65 + kp] = sa_u[((size_t)a * Bc + b) * 64 + kp];
    }
    __syncthreads();

    // ---- GEMM1: keys|vals (M=64, N=256, K=128) ----
    {
        int wcol = (wid >> 1) * 128;
        floatx4 acc[2][8];
#pragma unroll
        for (int mt = 0; mt < 2; ++mt)
#pragma unroll
            for (int nt = 0; nt < 8; ++nt)
#pragma unroll
                for (int e = 0; e < 4; ++e) acc[mt][nt][e] = 0.f;
#pragma unroll
        for (int s = 0; s < 4; ++s) {
            short8 afr[2];
#pragma unroll
            for (int mt = 0; mt < 2; ++mt)
                afr[mt] = ld_frag(&Xs[(wrow + mt * 16 + lm) * 65 + s * 16 + lq * 4]);
#pragma unroll
            for (int nt = 0; nt < 8; ++nt) {
                int col = wcol + nt * 16 + lm;
                short8 bfr = ld_frag(wt_p1 + (size_t)col * 64 + s * 16 + lq * 4);
#pragma unroll
                for (int mt = 0; mt < 2; ++mt)
                    acc[mt][nt] = __builtin_amdgcn_mfma_f32_16x16x32_bf16(
                        afr[mt], bfr, acc[mt][nt], 0, 0, 0);
            }
        }
#pragma unroll
        for (int mt = 0; mt < 2; ++mt)
#pragma unroll
            for (int nt = 0; nt < 8; ++nt)
#pragma unroll
                for (int r = 0; r < 4; ++r) {
                    int row = wrow + mt * 16 + lq * 4 + r;
                    int col = wcol + nt * 16 + lm;
                    float v = acc[mt][nt][r];
                    if (col < 128) {
                        keys_s[row * 130 + col] = f2bf(v);
                    } else {
                        int c2 = col - 128;
                        v += bv[c2];
                        v = v > 0.f ? v : 0.01f * v;
                        vals_s[row * 130 + c2] = f2bf(v);
                    }
                }
    }
    __syncthreads();

    // ---- load se rows (overwrite sa) ----
    for (int idx = t; idx < 64 * 64; idx += 256) {
        int r = idx >> 6, kp = idx & 63;
        int a = r >> 2, b = bg0 + (r & 3);
        Xs[r * 65 + kp] = se_u[((size_t)a * Bc + b) * 64 + kp];
    }
    __syncthreads();

    // ---- GEMM2: sel (M=64, N=128, K=128) ----
    {
        int wcol = (wid >> 1) * 64;
        floatx4 acc[2][4];
#pragma unroll
        for (int mt = 0; mt < 2; ++mt)
#pragma unroll
            for (int nt = 0; nt < 4; ++nt)
#pragma unroll
                for (int e = 0; e < 4; ++e) acc[mt][nt][e] = 0.f;
#pragma unroll
        for (int s = 0; s < 4; ++s) {
            short8 afr[2];
#pragma unroll
            for (int mt = 0; mt < 2; ++mt)
                afr[mt] = ld_frag(&Xs[(wrow + mt * 16 + lm) * 65 + s * 16 + lq * 4]);
#pragma unroll
            for (int nt = 0; nt < 4; ++nt) {
                int col = wcol + nt * 16 + lm;
                short8 bfr = ld_frag(wt_p2 + (size_t)col * 64 + s * 16 + lq * 4);
#pragma unroll
                for (int mt = 0; mt < 2; ++mt)
                    acc[mt][nt] = __builtin_amdgcn_mfma_f32_16x16x32_bf16(
                        afr[mt], bfr, acc[mt][nt], 0, 0, 0);
            }
        }
        __syncthreads();  // all waves done reading Xs(se) before sel overlay
#pragma unroll
        for (int mt = 0; mt < 2; ++mt)
#pragma unroll
            for (int nt = 0; nt < 4; ++nt)
#pragma unroll
                for (int r = 0; r < 4; ++r) {
                    int row = wrow + mt * 16 + lq * 4 + r;
                    int col = wcol + nt * 16 + lm;
                    sel_s[row * 130 + col] = f2bf(acc[mt][nt][r]);
                }
    }
    __syncthreads();

    // ---- attention: thread = (bsub, head n, agent i) ----
    int bsub = t >> 6, n = (t >> 4) & 3, i = t & 15;
    float sv[32];
    {
        const unsigned* srow = (const unsigned*)&sel_s[(i * 4 + bsub) * 130 + n * 32];
#pragma unroll
        for (int u = 0; u < 16; ++u) {
            unsigned x = srow[u];
            sv[2 * u] = bflo(x); sv[2 * u + 1] = bfhi(x);
        }
    }
    float lg[16];
#pragma unroll
    for (int j = 0; j < 16; ++j) {
        const unsigned* krow = (const unsigned*)&keys_s[(j * 4 + bsub) * 130 + n * 32];
        float d = 0.f;
#pragma unroll
        for (int u = 0; u < 16; ++u) {
            unsigned x = krow[u];
            d = fmaf(sv[2 * u], bflo(x), d);
            d = fmaf(sv[2 * u + 1], bfhi(x), d);
        }
        lg[j] = d * 0.17677669529663687f;
    }
    lg[i] = NEGV;
    float m = lg[0];
#pragma unroll
    for (int j = 1; j < 16; ++j) m = fmaxf(m, lg[j]);
    float sum = 0.f;
#pragma unroll
    for (int j = 0; j < 16; ++j) { lg[j] = __expf(lg[j] - m); sum += lg[j]; }
    float inv = 1.f / sum;
#pragma unroll
    for (int j = 0; j < 16; ++j) lg[j] *= inv;

    float ov[32];
#pragma unroll
    for (int u = 0; u < 32; ++u) ov[u] = 0.f;
#pragma unroll
    for (int j = 0; j < 16; ++j) {
        const unsigned* vrow = (const unsigned*)&vals_s[(j * 4 + bsub) * 130 + n * 32];
        float w = lg[j];
#pragma unroll
        for (int u = 0; u < 16; ++u) {
            unsigned x = vrow[u];
            ov[2 * u] = fmaf(w, bflo(x), ov[2 * u]);
            ov[2 * u + 1] = fmaf(w, bfhi(x), ov[2 * u + 1]);
        }
    }
    {
        unsigned* orow = (unsigned*)&other_us[((size_t)i * Bc + bg0 + bsub) * 128 + n * 32];
#pragma unroll
        for (int w4 = 0; w4 < 4; ++w4) {
            uint4 o;
            o.x = pack_bf2(ov[8 * w4 + 0], ov[8 * w4 + 1]);
            o.y = pack_bf2(ov[8 * w4 + 2], ov[8 * w4 + 3]);
            o.z = pack_bf2(ov[8 * w4 + 4], ov[8 * w4 + 5]);
            o.w = pack_bf2(ov[8 * w4 + 6], ov[8 * w4 + 7]);
            ((uint4*)orow)[w4] = o;
        }
    }
}

// ---- critic: h = lrelu([se|other] @ Wc1 + bc1); q = h.Wc2[:,argmax]+bc2 --
__global__ __launch_bounds__(256) void k_critic(
    const unsigned* __restrict__ se_u, const unsigned* __restrict__ other_u,
    const unsigned* __restrict__ wt_cr,
    const float* __restrict__ bc1, const float* __restrict__ actions,
    const float* __restrict__ Wc2, const float* __restrict__ bc2,
    float* __restrict__ qout, int b0g, int Bc) {
    __shared__ unsigned smem[(128 + 128) * 34];  // 34816 B
    unsigned* Xs = smem;
    unsigned* Ws = smem + 128 * 34;

    int a = blockIdx.y;
    int b0 = blockIdx.x * 128;
    int t = threadIdx.x;
    int wid = t >> 6, lane = t & 63, lm = lane & 15, lq = lane >> 4;
    int wrow = (wid & 1) * 64;
    int wcol = (wid >> 1) * 64;

    floatx4 acc[4][4];
#pragma unroll
    for (int mt = 0; mt < 4; ++mt)
#pragma unroll
        for (int nt = 0; nt < 4; ++nt)
#pragma unroll
            for (int e = 0; e < 4; ++e) acc[mt][nt][e] = 0.f;

    const unsigned* WtA = wt_cr + (size_t)a * 16384;

    for (int c = 0; c < 4; ++c) {
        int kk = c * 64;
        __syncthreads();
        const unsigned* src = (c < 2) ? se_u : other_u;
        int off = (c & 1) * 32;
        for (int idx = t; idx < 128 * 32; idx += 256) {
            int r = idx >> 5, kp = idx & 31;
            Xs[r * 34 + kp] = src[((size_t)a * Bc + b0 + r) * 64 + off + kp];
        }
        for (int idx = t; idx < 128 * 32; idx += 256) {
            int n = idx >> 5, kp = idx & 31;
            Ws[n * 34 + kp] = WtA[(size_t)n * 128 + (kk >> 1) + kp];
        }
        __syncthreads();
#pragma unroll
        for (int s = 0; s < 2; ++s) {
            short8 afr[4];
#pragma unroll
            for (int mt = 0; mt < 4; ++mt)
                afr[mt] = ld_frag(&Xs[(wrow + mt * 16 + lm) * 34 + s * 16 + lq * 4]);
#pragma unroll
            for (int nt = 0; nt < 4; ++nt) {
                short8 bfr = ld_frag(&Ws[(wcol + nt * 16 + lm) * 34 + s * 16 + lq * 4]);
#pragma unroll
                for (int mt = 0; mt < 4; ++mt)
                    acc[mt][nt] = __builtin_amdgcn_mfma_f32_16x16x32_bf16(
                        afr[mt], bfr, acc[mt][nt], 0, 0, 0);
            }
        }
    }

    __syncthreads();
    unsigned short* hbuf = (unsigned short*)smem;  // [128][132]
#pragma unroll
    for (int mt = 0; mt < 4; ++mt)
#pragma unroll
        for (int nt = 0; nt < 4; ++nt)
#pragma unroll
            for (int r = 0; r < 4; ++r) {
                int row = wrow + mt * 16 + lq * 4 + r;
                int col = wcol + nt * 16 + lm;
                float v = acc[mt][nt][r] + bc1[a * H_N + col];
                v = v > 0.f ? v : 0.01f * v;
                hbuf[row * 132 + col] = f2bf(v);
            }
    __syncthreads();
    if (t < 128) {
        size_t arow = (size_t)a * B_N + b0g + b0 + t;
        const float* ap = &actions[arow * ACT_N];
        float bestv = ap[0];
        int bi = 0;
        for (int o = 1; o < ACT_N; ++o) {
            float v = ap[o];
            if (v > bestv) { bestv = v; bi = o; }
        }
        float q = bc2[a * ACT_N + bi];
        const float* w2 = &Wc2[((size_t)a * H_N) * ACT_N + bi];
        const unsigned short* hp = &hbuf[t * 132];
#pragma unroll 8
        for (int h = 0; h < H_N; ++h)
            q = fmaf(bf2f(hp[h]), w2[(size_t)h * ACT_N], q);
        qout[arow] = q;
    }
}

extern "C" void kernel_launch(void* const* d_in, const int* in_sizes, int n_in,
                              void* d_out, int out_size, void* d_ws, size_t ws_size,
                              hipStream_t stream) {
    const float* obs     = (const float*)d_in[0];
    const float* actions = (const float*)d_in[1];
    const float* W_sa    = (const float*)d_in[2];
    const float* b_sa    = (const float*)d_in[3];
    const float* W_s     = (const float*)d_in[4];
    const float* b_s     = (const float*)d_in[5];
    const float* Wk      = (const float*)d_in[6];
    const float* Wsel    = (const float*)d_in[7];
    const float* Wv      = (const float*)d_in[8];
    const float* bv      = (const float*)d_in[9];
    const float* Wc1     = (const float*)d_in[10];
    const float* bc1     = (const float*)d_in[11];
    const float* Wc2     = (const float*)d_in[12];
    const float* bc2     = (const float*)d_in[13];
    float* out = (float*)d_out;
    char* ws = (char*)d_ws;

    size_t o = 0;
    float* gsum = (float*)(ws + o); o += 2304 * 4;
    float* gsq  = (float*)(ws + o); o += 2304 * 4;
    unsigned* wt_l1 = (unsigned*)(ws + o); o += (size_t)393216 * 4;
    unsigned* wt_p1 = (unsigned*)(ws + o); o += (size_t)16384 * 4;
    unsigned* wt_p2 = (unsigned*)(ws + o); o += (size_t)8192 * 4;
    unsigned* wt_cr = (unsigned*)(ws + o); o += (size_t)262144 * 4;
    size_t fixed = o;

    // Per-slice: sa, se, other — each [16][Bc][128] bf16 = 4096*Bc B.
    int Bc = B_N;
    while (Bc > 128 && fixed + 12288ull * Bc > ws_size) Bc >>= 1;

    unsigned short* sa_us = (unsigned short*)(ws + o); o += (size_t)A_N * Bc * 128 * 2;
    unsigned short* se_us = (unsigned short*)(ws + o); o += (size_t)A_N * Bc * 128 * 2;
    unsigned short* ot_us = (unsigned short*)(ws + o); o += (size_t)A_N * Bc * 128 * 2;

    k_zero<<<dim3(18), 256, 0, stream>>>(gsum, 2 * A_N * IN_N);
    k_stats<<<dim3(A_N * 32), 256, 0, stream>>>(obs, actions, gsum, gsq);
    k_finalize<<<dim3(9), 256, 0, stream>>>(gsum, gsq);
    k_wprep<<<dim3(CRE / 256), 256, 0, stream>>>(W_sa, W_s, Wk, Wsel, Wv, Wc1,
                                                 wt_l1, wt_p1, wt_p2, wt_cr);

    for (int b0g = 0; b0g < B_N; b0g += Bc) {
        dim3 gg(Bc / 128, A_N);
        k_l1<<<gg, 256, 0, stream>>>(obs, actions, gsum, gsq, wt_l1, b_sa, b_s,
                                     sa_us, se_us, b0g, Bc);
        k_fused<<<dim3(Bc / 4), 256, 0, stream>>>(
            (const unsigned*)sa_us, (const unsigned*)se_us, wt_p1, wt_p2, bv,
            ot_us, Bc);
        k_critic<<<gg, 256, 0, stream>>>(
            (const unsigned*)se_us, (const unsigned*)ot_us, wt_cr, bc1,
            actions, Wc2, bc2, out, b0g, Bc);
    }
}

// Round 5
// 349.320 us; speedup vs baseline: 3.2420x; 1.4258x over previous
//
#include <hip/hip_runtime.h>
#include <hip/hip_bf16.h>

#define A_N 16
#define B_N 8192
#define O_N 128
#define ACT_N 16
#define H_N 128
#define NH_N 4
#define D_N 32
#define IN_N 144
#define NEGV -1e9f

typedef __attribute__((ext_vector_type(8))) short short8;
typedef __attribute__((ext_vector_type(4))) float floatx4;

// ---- bf16 helpers (RNE) -------------------------------------------------
static __device__ inline unsigned short f2bf(float f) {
    union { float f; unsigned u; } x{f};
    unsigned u = x.u + 0x7FFFu + ((x.u >> 16) & 1u);
    return (unsigned short)(u >> 16);
}
static __device__ inline unsigned pack_bf2(float a, float b) {
    union { float f; unsigned u; } xa{a}, xb{b};
    unsigned ua = xa.u + 0x7FFFu + ((xa.u >> 16) & 1u);
    unsigned ub = xb.u + 0x7FFFu + ((xb.u >> 16) & 1u);
    return (ua >> 16) | (ub & 0xFFFF0000u);
}
static __device__ inline float bf2f(unsigned short h) {
    union { unsigned u; float f; } x;
    x.u = ((unsigned)h) << 16;
    return x.f;
}
static __device__ inline float bflo(unsigned u) {
    union { unsigned u; float f; } x; x.u = u << 16; return x.f;
}
static __device__ inline float bfhi(unsigned u) {
    union { unsigned u; float f; } x; x.u = u & 0xFFFF0000u; return x.f;
}
static __device__ inline short8 ld_frag(const unsigned* p) {
    union { unsigned u[4]; short8 v; } x;
    uint2 lo = *(const uint2*)p;
    uint2 hi = *(const uint2*)(p + 2);
    x.u[0] = lo.x; x.u[1] = lo.y; x.u[2] = hi.x; x.u[3] = hi.y;
    return x.v;
}

// ---- misc small kernels -------------------------------------------------
__global__ __launch_bounds__(256) void k_zero(float* p, int n) {
    int i = blockIdx.x * 256 + threadIdx.x;
    if (i < n) p[i] = 0.f;
}

__global__ __launch_bounds__(256) void k_stats(const float* __restrict__ obs,
                                               const float* __restrict__ act,
                                               float* __restrict__ gsum,
                                               float* __restrict__ gsq) {
    __shared__ float ssum[IN_N];
    __shared__ float ssq[IN_N];
    int a = blockIdx.x >> 5;
    int r0 = (blockIdx.x & 31) * 256;
    int t = threadIdx.x;
    if (t < IN_N) { ssum[t] = 0.f; ssq[t] = 0.f; }
    __syncthreads();
    if (t < 128) {
        const float* p = obs + ((size_t)a * B_N + r0) * O_N + t;
        float s = 0.f, q = 0.f;
#pragma unroll 4
        for (int r = 0; r < 256; ++r) {
            float v = p[(size_t)r * O_N];
            s += v; q += v * v;
        }
        ssum[t] = s; ssq[t] = q;
    } else {
        int tt = t - 128;
        int f = tt & 15, rg = tt >> 4;
        const float* p = act + ((size_t)a * B_N + r0 + rg) * ACT_N + f;
        float s = 0.f, q = 0.f;
#pragma unroll 4
        for (int i = 0; i < 32; ++i) {
            float v = p[(size_t)i * 8 * ACT_N];
            s += v; q += v * v;
        }
        atomicAdd(&ssum[O_N + f], s);
        atomicAdd(&ssq[O_N + f], q);
    }
    __syncthreads();
    if (t < IN_N) {
        atomicAdd(&gsum[a * IN_N + t], ssum[t]);
        atomicAdd(&gsq[a * IN_N + t], ssq[t]);
    }
}

__global__ __launch_bounds__(256) void k_finalize(float* gsum, float* gsq) {
    int i = blockIdx.x * 256 + threadIdx.x;
    if (i < A_N * IN_N) {
        const float invB = 1.f / (float)B_N;
        float m = gsum[i] * invB;
        float v = fmaxf(gsq[i] * invB - m * m, 0.f);
        gsum[i] = m;
        gsq[i] = rsqrtf(v + 1e-5f);
    }
}

// ---- weight prep: fp32 -> bf16, transposed to [n][k/2] packed uints -----
#define L1E 393216
#define P1E 409600
#define P2E 417792
#define CRE 679936
__global__ __launch_bounds__(256) void k_wprep(
    const float* __restrict__ W_sa, const float* __restrict__ W_s,
    const float* __restrict__ Wk, const float* __restrict__ Wsel,
    const float* __restrict__ Wv, const float* __restrict__ Wc1,
    unsigned* __restrict__ wt_l1, unsigned* __restrict__ wt_p1,
    unsigned* __restrict__ wt_p2, unsigned* __restrict__ wt_cr) {
    int idx = blockIdx.x * 256 + threadIdx.x;
    if (idx < L1E) {
        int a = idx / 24576, rem = idx % 24576;
        int n = rem & 255, kp = rem >> 8;  // kp 0..95
        int k0 = 2 * kp, k1 = k0 + 1;
        float v0, v1;
        if (n < 128) {
            v0 = (k0 < IN_N) ? W_sa[((size_t)a * IN_N + k0) * H_N + n] : 0.f;
            v1 = (k1 < IN_N) ? W_sa[((size_t)a * IN_N + k1) * H_N + n] : 0.f;
        } else {
            int m = n - 128;
            v0 = (k0 < O_N) ? W_s[((size_t)a * O_N + k0) * H_N + m] : 0.f;
            v1 = (k1 < O_N) ? W_s[((size_t)a * O_N + k1) * H_N + m] : 0.f;
        }
        wt_l1[(size_t)a * 24576 + n * 96 + kp] = pack_bf2(v0, v1);
    } else if (idx < P1E) {
        int i2 = idx - L1E;
        int n = i2 & 255, kp = i2 >> 8;  // kp 0..63
        int k0 = 2 * kp;
        float v0, v1;
        if (n < 128) {
            const float* w = Wk + ((size_t)(n >> 5) * H_N) * D_N + (n & 31);
            v0 = w[(size_t)k0 * D_N]; v1 = w[(size_t)(k0 + 1) * D_N];
        } else {
            int m = n - 128;
            const float* w = Wv + ((size_t)(m >> 5) * H_N) * D_N + (m & 31);
            v0 = w[(size_t)k0 * D_N]; v1 = w[(size_t)(k0 + 1) * D_N];
        }
        wt_p1[n * 64 + kp] = pack_bf2(v0, v1);
    } else if (idx < P2E) {
        int i3 = idx - P1E;
        int n = i3 & 127, kp = i3 >> 7;
        int k0 = 2 * kp;
        const float* w = Wsel + ((size_t)(n >> 5) * H_N) * D_N + (n & 31);
        wt_p2[n * 64 + kp] = pack_bf2(w[(size_t)k0 * D_N], w[(size_t)(k0 + 1) * D_N]);
    } else if (idx < CRE) {
        int i4 = idx - P2E;
        int a = i4 >> 14, r = i4 & 16383;
        int n = r & 127, kp = r >> 7;  // kp 0..127
        int k0 = 2 * kp;
        const float* w = Wc1 + (size_t)a * 256 * H_N + n;
        wt_cr[(size_t)a * 16384 + n * 128 + kp] =
            pack_bf2(w[(size_t)k0 * H_N], w[(size_t)(k0 + 1) * H_N]);
    }
}

// ---- L1: grid.z=0 -> sa (K=160), grid.z=1 -> se (K=128) -----------------
// Block 128 rows x 128 cols, 4 waves 2x2, wave 64x64, acc[4][4] (64 AGPR).
__global__ __launch_bounds__(256, 3) void k_l1(
    const float* __restrict__ obs, const float* __restrict__ act,
    const float* __restrict__ mean, const float* __restrict__ rstd,
    const unsigned* __restrict__ wt_l1,
    const float* __restrict__ b_sa, const float* __restrict__ b_s,
    unsigned short* __restrict__ sa_us, unsigned short* __restrict__ se_us,
    int b0g, int Bc) {
    __shared__ unsigned smem[(128 + 128) * 34];  // 34816 B
    unsigned* Xs = smem;
    unsigned* Ws = smem + 128 * 34;

    int a = blockIdx.y;
    int z = blockIdx.z;
    int b0 = blockIdx.x * 128;
    int t = threadIdx.x;
    int wid = t >> 6, lane = t & 63, lm = lane & 15, lq = lane >> 4;
    int wrow = (wid & 1) * 64;
    int wcol = (wid >> 1) * 64;

    int colbase = z * 128;
    int kchunks = z ? 2 : 3;
    int kstop = z ? 128 : 160;
    const float* bias = z ? b_s : b_sa;
    unsigned short* outp = z ? se_us : sa_us;

    floatx4 acc[4][4];
#pragma unroll
    for (int mt = 0; mt < 4; ++mt)
#pragma unroll
        for (int nt = 0; nt < 4; ++nt)
#pragma unroll
            for (int e = 0; e < 4; ++e) acc[mt][nt][e] = 0.f;

    const unsigned* WtA = wt_l1 + (size_t)a * 24576 + (size_t)colbase * 96;

    for (int c = 0; c < kchunks; ++c) {
        int kk = c * 64;
        __syncthreads();
        for (int idx = t; idx < 128 * 32; idx += 256) {
            int r = idx >> 5, kp = idx & 31;
            int k = kk + 2 * kp;  // even
            float v0 = 0.f, v1 = 0.f;
            if (k < IN_N) {
                size_t grow = (size_t)a * B_N + b0g + b0 + r;
                float x0 = (k < O_N) ? obs[grow * O_N + k]
                                     : act[grow * ACT_N + k - O_N];
                float x1 = (k + 1 < O_N) ? obs[grow * O_N + k + 1]
                                         : act[grow * ACT_N + k + 1 - O_N];
                v0 = (x0 - mean[a * IN_N + k]) * rstd[a * IN_N + k];
                v1 = (x1 - mean[a * IN_N + k + 1]) * rstd[a * IN_N + k + 1];
            }
            Xs[r * 34 + kp] = pack_bf2(v0, v1);
        }
        for (int idx = t; idx < 128 * 32; idx += 256) {
            int n = idx >> 5, kp = idx & 31;
            Ws[n * 34 + kp] = WtA[(size_t)n * 96 + (kk >> 1) + kp];
        }
        __syncthreads();
#pragma unroll
        for (int s = 0; s < 2; ++s) {
            if (kk + s * 32 >= kstop) break;
            short8 afr[4];
#pragma unroll
            for (int mt = 0; mt < 4; ++mt)
                afr[mt] = ld_frag(&Xs[(wrow + mt * 16 + lm) * 34 + s * 16 + lq * 4]);
#pragma unroll
            for (int nt = 0; nt < 4; ++nt) {
                short8 bfr = ld_frag(&Ws[(wcol + nt * 16 + lm) * 34 + s * 16 + lq * 4]);
#pragma unroll
                for (int mt = 0; mt < 4; ++mt)
                    acc[mt][nt] = __builtin_amdgcn_mfma_f32_16x16x32_bf16(
                        afr[mt], bfr, acc[mt][nt], 0, 0, 0);
            }
        }
    }

#pragma unroll
    for (int mt = 0; mt < 4; ++mt)
#pragma unroll
        for (int nt = 0; nt < 4; ++nt)
#pragma unroll
            for (int r = 0; r < 4; ++r) {
                int row = b0 + wrow + mt * 16 + lq * 4 + r;
                int col = wcol + nt * 16 + lm;
                float v = acc[mt][nt][r] + bias[a * H_N + col];
                v = v > 0.f ? v : 0.01f * v;
                outp[((size_t)a * Bc + row) * 128 + col] = f2bf(v);
            }
}

// ---- fused: keys|vals|sel GEMMs (LDS-only) + attention -> other (bf16) --
// Block = 4 batch elems x 16 agents = 64 rows. Weights read from L2 as frags.
__global__ __launch_bounds__(256, 3) void k_fused(
    const unsigned* __restrict__ sa_u, const unsigned* __restrict__ se_u,
    const unsigned* __restrict__ wt_p1, const unsigned* __restrict__ wt_p2,
    const float* __restrict__ bv, unsigned short* __restrict__ other_us,
    int Bc) {
    __shared__ unsigned Xs[64 * 65];            // 16640 B (sa, then se; sel after)
    __shared__ unsigned short keys_s[64 * 130]; // 16640 B
    __shared__ unsigned short vals_s[64 * 130]; // 16640 B
    unsigned short* sel_s = (unsigned short*)Xs;

    int bg0 = blockIdx.x * 4;
    int t = threadIdx.x;
    int wid = t >> 6, lane = t & 63, lm = lane & 15, lq = lane >> 4;
    int wrow = (wid & 1) * 32;
    int wcol = (wid >> 1) * 64;

    // ---- load sa rows [64][64 uints] ----
    for (int idx = t; idx < 64 * 64; idx += 256) {
        int r = idx >> 6, kp = idx & 63;
        int a = r >> 2, b = bg0 + (r & 3);
        Xs[r * 65 + kp] = sa_u[((size_t)a * Bc + b) * 64 + kp];
    }
    __syncthreads();

    // ---- GEMM pass 1: keys (cols 0..127 of wt_p1), acc[2][4] ----
#pragma unroll
    for (int pass = 0; pass < 2; ++pass) {
        floatx4 acc[2][4];
#pragma unroll
        for (int mt = 0; mt < 2; ++mt)
#pragma unroll
            for (int nt = 0; nt < 4; ++nt)
#pragma unroll
                for (int e = 0; e < 4; ++e) acc[mt][nt][e] = 0.f;
        const unsigned* wbase = wt_p1 + (size_t)(pass * 128) * 64;
#pragma unroll
        for (int s = 0; s < 4; ++s) {
            short8 afr[2];
#pragma unroll
            for (int mt = 0; mt < 2; ++mt)
                afr[mt] = ld_frag(&Xs[(wrow + mt * 16 + lm) * 65 + s * 16 + lq * 4]);
#pragma unroll
            for (int nt = 0; nt < 4; ++nt) {
                int col = wcol + nt * 16 + lm;
                short8 bfr = ld_frag(wbase + (size_t)col * 64 + s * 16 + lq * 4);
#pragma unroll
                for (int mt = 0; mt < 2; ++mt)
                    acc[mt][nt] = __builtin_amdgcn_mfma_f32_16x16x32_bf16(
                        afr[mt], bfr, acc[mt][nt], 0, 0, 0);
            }
        }
#pragma unroll
        for (int mt = 0; mt < 2; ++mt)
#pragma unroll
            for (int nt = 0; nt < 4; ++nt)
#pragma unroll
                for (int r = 0; r < 4; ++r) {
                    int row = wrow + mt * 16 + lq * 4 + r;
                    int col = wcol + nt * 16 + lm;
                    float v = acc[mt][nt][r];
                    if (pass == 0) {
                        keys_s[row * 130 + col] = f2bf(v);
                    } else {
                        v += bv[col];
                        v = v > 0.f ? v : 0.01f * v;
                        vals_s[row * 130 + col] = f2bf(v);
                    }
                }
    }
    __syncthreads();

    // ---- load se rows (overwrite sa) ----
    for (int idx = t; idx < 64 * 64; idx += 256) {
        int r = idx >> 6, kp = idx & 63;
        int a = r >> 2, b = bg0 + (r & 3);
        Xs[r * 65 + kp] = se_u[((size_t)a * Bc + b) * 64 + kp];
    }
    __syncthreads();

    // ---- GEMM2: sel (M=64, N=128, K=128), acc[2][4] ----
    {
        floatx4 acc[2][4];
#pragma unroll
        for (int mt = 0; mt < 2; ++mt)
#pragma unroll
            for (int nt = 0; nt < 4; ++nt)
#pragma unroll
                for (int e = 0; e < 4; ++e) acc[mt][nt][e] = 0.f;
#pragma unroll
        for (int s = 0; s < 4; ++s) {
            short8 afr[2];
#pragma unroll
            for (int mt = 0; mt < 2; ++mt)
                afr[mt] = ld_frag(&Xs[(wrow + mt * 16 + lm) * 65 + s * 16 + lq * 4]);
#pragma unroll
            for (int nt = 0; nt < 4; ++nt) {
                int col = wcol + nt * 16 + lm;
                short8 bfr = ld_frag(wt_p2 + (size_t)col * 64 + s * 16 + lq * 4);
#pragma unroll
                for (int mt = 0; mt < 2; ++mt)
                    acc[mt][nt] = __builtin_amdgcn_mfma_f32_16x16x32_bf16(
                        afr[mt], bfr, acc[mt][nt], 0, 0, 0);
            }
        }
        __syncthreads();  // all waves done reading Xs(se) before sel overlay
#pragma unroll
        for (int mt = 0; mt < 2; ++mt)
#pragma unroll
            for (int nt = 0; nt < 4; ++nt)
#pragma unroll
                for (int r = 0; r < 4; ++r) {
                    int row = wrow + mt * 16 + lq * 4 + r;
                    int col = wcol + nt * 16 + lm;
                    sel_s[row * 130 + col] = f2bf(acc[mt][nt][r]);
                }
    }
    __syncthreads();

    // ---- attention: thread = (bsub, head n, agent i) ----
    int bsub = t >> 6, n = (t >> 4) & 3, i = t & 15;
    unsigned sv_u[16];
    {
        const unsigned* srow = (const unsigned*)&sel_s[(i * 4 + bsub) * 130 + n * 32];
#pragma unroll
        for (int u = 0; u < 16; ++u) sv_u[u] = srow[u];
    }
    float lg[16];
#pragma unroll
    for (int j = 0; j < 16; ++j) {
        const unsigned* krow = (const unsigned*)&keys_s[(j * 4 + bsub) * 130 + n * 32];
        float d = 0.f;
#pragma unroll
        for (int u = 0; u < 16; ++u) {
            unsigned x = krow[u];
            d = fmaf(bflo(sv_u[u]), bflo(x), d);
            d = fmaf(bfhi(sv_u[u]), bfhi(x), d);
        }
        lg[j] = d * 0.17677669529663687f;
    }
    lg[i] = NEGV;
    float m = lg[0];
#pragma unroll
    for (int j = 1; j < 16; ++j) m = fmaxf(m, lg[j]);
    float sum = 0.f;
#pragma unroll
    for (int j = 0; j < 16; ++j) { lg[j] = __expf(lg[j] - m); sum += lg[j]; }
    float inv = 1.f / sum;
#pragma unroll
    for (int j = 0; j < 16; ++j) lg[j] *= inv;

    unsigned* orow = (unsigned*)&other_us[((size_t)i * Bc + bg0 + bsub) * 128 + n * 32];
#pragma unroll
    for (int half = 0; half < 2; ++half) {
        float ov[16];
#pragma unroll
        for (int u = 0; u < 16; ++u) ov[u] = 0.f;
#pragma unroll
        for (int j = 0; j < 16; ++j) {
            const unsigned* vrow =
                (const unsigned*)&vals_s[(j * 4 + bsub) * 130 + n * 32 + half * 16];
            float w = lg[j];
#pragma unroll
            for (int u = 0; u < 8; ++u) {
                unsigned x = vrow[u];
                ov[2 * u] = fmaf(w, bflo(x), ov[2 * u]);
                ov[2 * u + 1] = fmaf(w, bfhi(x), ov[2 * u + 1]);
            }
        }
        uint4 o0, o1;
        o0.x = pack_bf2(ov[0], ov[1]);  o0.y = pack_bf2(ov[2], ov[3]);
        o0.z = pack_bf2(ov[4], ov[5]);  o0.w = pack_bf2(ov[6], ov[7]);
        o1.x = pack_bf2(ov[8], ov[9]);  o1.y = pack_bf2(ov[10], ov[11]);
        o1.z = pack_bf2(ov[12], ov[13]); o1.w = pack_bf2(ov[14], ov[15]);
        ((uint4*)orow)[half * 2] = o0;
        ((uint4*)orow)[half * 2 + 1] = o1;
    }
}

// ---- critic: block 64 rows x 128 cols, wave 32x64, acc[2][4] ------------
__global__ __launch_bounds__(256, 3) void k_critic(
    const unsigned* __restrict__ se_u, const unsigned* __restrict__ other_u,
    const unsigned* __restrict__ wt_cr,
    const float* __restrict__ bc1, const float* __restrict__ actions,
    const float* __restrict__ Wc2, const float* __restrict__ bc2,
    float* __restrict__ qout, int b0g, int Bc) {
    __shared__ unsigned smem[(64 + 128) * 34];  // 26112 B
    unsigned* Xs = smem;
    unsigned* Ws = smem + 64 * 34;

    int a = blockIdx.y;
    int b0 = blockIdx.x * 64;
    int t = threadIdx.x;
    int wid = t >> 6, lane = t & 63, lm = lane & 15, lq = lane >> 4;
    int wrow = (wid & 1) * 32;
    int wcol = (wid >> 1) * 64;

    floatx4 acc[2][4];
#pragma unroll
    for (int mt = 0; mt < 2; ++mt)
#pragma unroll
        for (int nt = 0; nt < 4; ++nt)
#pragma unroll
            for (int e = 0; e < 4; ++e) acc[mt][nt][e] = 0.f;

    const unsigned* WtA = wt_cr + (size_t)a * 16384;

    for (int c = 0; c < 4; ++c) {
        int kk = c * 64;
        __syncthreads();
        const unsigned* src = (c < 2) ? se_u : other_u;
        int off = (c & 1) * 32;
        for (int idx = t; idx < 64 * 32; idx += 256) {
            int r = idx >> 5, kp = idx & 31;
            Xs[r * 34 + kp] = src[((size_t)a * Bc + b0 + r) * 64 + off + kp];
        }
        for (int idx = t; idx < 128 * 32; idx += 256) {
            int n = idx >> 5, kp = idx & 31;
            Ws[n * 34 + kp] = WtA[(size_t)n * 128 + (kk >> 1) + kp];
        }
        __syncthreads();
#pragma unroll
        for (int s = 0; s < 2; ++s) {
            short8 afr[2];
#pragma unroll
            for (int mt = 0; mt < 2; ++mt)
                afr[mt] = ld_frag(&Xs[(wrow + mt * 16 + lm) * 34 + s * 16 + lq * 4]);
#pragma unroll
            for (int nt = 0; nt < 4; ++nt) {
                short8 bfr = ld_frag(&Ws[(wcol + nt * 16 + lm) * 34 + s * 16 + lq * 4]);
#pragma unroll
                for (int mt = 0; mt < 2; ++mt)
                    acc[mt][nt] = __builtin_amdgcn_mfma_f32_16x16x32_bf16(
                        afr[mt], bfr, acc[mt][nt], 0, 0, 0);
            }
        }
    }

    __syncthreads();
    unsigned short* hbuf = (unsigned short*)smem;  // [64][132] = 16896 B
#pragma unroll
    for (int mt = 0; mt < 2; ++mt)
#pragma unroll
        for (int nt = 0; nt < 4; ++nt)
#pragma unroll
            for (int r = 0; r < 4; ++r) {
                int row = wrow + mt * 16 + lq * 4 + r;
                int col = wcol + nt * 16 + lm;
                float v = acc[mt][nt][r] + bc1[a * H_N + col];
                v = v > 0.f ? v : 0.01f * v;
                hbuf[row * 132 + col] = f2bf(v);
            }
    __syncthreads();
    if (t < 64) {
        size_t arow = (size_t)a * B_N + b0g + b0 + t;
        const float* ap = &actions[arow * ACT_N];
        float bestv = ap[0];
        int bi = 0;
        for (int o = 1; o < ACT_N; ++o) {
            float v = ap[o];
            if (v > bestv) { bestv = v; bi = o; }
        }
        float q = bc2[a * ACT_N + bi];
        const float* w2 = &Wc2[((size_t)a * H_N) * ACT_N + bi];
        const unsigned short* hp = &hbuf[t * 132];
#pragma unroll 8
        for (int h = 0; h < H_N; ++h)
            q = fmaf(bf2f(hp[h]), w2[(size_t)h * ACT_N], q);
        qout[arow] = q;
    }
}

extern "C" void kernel_launch(void* const* d_in, const int* in_sizes, int n_in,
                              void* d_out, int out_size, void* d_ws, size_t ws_size,
                              hipStream_t stream) {
    const float* obs     = (const float*)d_in[0];
    const float* actions = (const float*)d_in[1];
    const float* W_sa    = (const float*)d_in[2];
    const float* b_sa    = (const float*)d_in[3];
    const float* W_s     = (const float*)d_in[4];
    const float* b_s     = (const float*)d_in[5];
    const float* Wk      = (const float*)d_in[6];
    const float* Wsel    = (const float*)d_in[7];
    const float* Wv      = (const float*)d_in[8];
    const float* bv      = (const float*)d_in[9];
    const float* Wc1     = (const float*)d_in[10];
    const float* bc1     = (const float*)d_in[11];
    const float* Wc2     = (const float*)d_in[12];
    const float* bc2     = (const float*)d_in[13];
    float* out = (float*)d_out;
    char* ws = (char*)d_ws;

    size_t o = 0;
    float* gsum = (float*)(ws + o); o += 2304 * 4;
    float* gsq  = (float*)(ws + o); o += 2304 * 4;
    unsigned* wt_l1 = (unsigned*)(ws + o); o += (size_t)393216 * 4;
    unsigned* wt_p1 = (unsigned*)(ws + o); o += (size_t)16384 * 4;
    unsigned* wt_p2 = (unsigned*)(ws + o); o += (size_t)8192 * 4;
    unsigned* wt_cr = (unsigned*)(ws + o); o += (size_t)262144 * 4;
    size_t fixed = o;

    // Per-slice: sa, se, other — each [16][Bc][128] bf16 = 4096*Bc B.
    int Bc = B_N;
    while (Bc > 128 && fixed + 12288ull * Bc > ws_size) Bc >>= 1;

    unsigned short* sa_us = (unsigned short*)(ws + o); o += (size_t)A_N * Bc * 128 * 2;
    unsigned short* se_us = (unsigned short*)(ws + o); o += (size_t)A_N * Bc * 128 * 2;
    unsigned short* ot_us = (unsigned short*)(ws + o); o += (size_t)A_N * Bc * 128 * 2;

    k_zero<<<dim3(18), 256, 0, stream>>>(gsum, 2 * A_N * IN_N);
    k_stats<<<dim3(A_N * 32), 256, 0, stream>>>(obs, actions, gsum, gsq);
    k_finalize<<<dim3(9), 256, 0, stream>>>(gsum, gsq);
    k_wprep<<<dim3(CRE / 256), 256, 0, stream>>>(W_sa, W_s, Wk, Wsel, Wv, Wc1,
                                                 wt_l1, wt_p1, wt_p2, wt_cr);

    for (int b0g = 0; b0g < B_N; b0g += Bc) {
        k_l1<<<dim3(Bc / 128, A_N, 2), 256, 0, stream>>>(
            obs, actions, gsum, gsq, wt_l1, b_sa, b_s, sa_us, se_us, b0g, Bc);
        k_fused<<<dim3(Bc / 4), 256, 0, stream>>>(
            (const unsigned*)sa_us, (const unsigned*)se_us, wt_p1, wt_p2, bv,
            ot_us, Bc);
        k_critic<<<dim3(Bc / 64, A_N), 256, 0, stream>>>(
            (const unsigned*)se_us, (const unsigned*)ot_us, wt_cr, bc1,
            actions, Wc2, bc2, out, b0g, Bc);
    }
}

// Round 6
// 343.705 us; speedup vs baseline: 3.2950x; 1.0163x over previous
//
#include <hip/hip_runtime.h>
#include <hip/hip_bf16.h>

#define A_N 16
#define B_N 8192
#define O_N 128
#define ACT_N 16
#define H_N 128
#define NH_N 4
#define D_N 32
#define IN_N 144
#define NEGV -1e9f

typedef __attribute__((ext_vector_type(8))) short short8;
typedef __attribute__((ext_vector_type(4))) float floatx4;

// ---- bf16 helpers (RNE) -------------------------------------------------
static __device__ inline unsigned short f2bf(float f) {
    union { float f; unsigned u; } x{f};
    unsigned u = x.u + 0x7FFFu + ((x.u >> 16) & 1u);
    return (unsigned short)(u >> 16);
}
static __device__ inline unsigned pack_bf2(float a, float b) {
    union { float f; unsigned u; } xa{a}, xb{b};
    unsigned ua = xa.u + 0x7FFFu + ((xa.u >> 16) & 1u);
    unsigned ub = xb.u + 0x7FFFu + ((xb.u >> 16) & 1u);
    return (ua >> 16) | (ub & 0xFFFF0000u);
}
static __device__ inline float bf2f(unsigned short h) {
    union { unsigned u; float f; } x;
    x.u = ((unsigned)h) << 16;
    return x.f;
}
static __device__ inline float bflo(unsigned u) {
    union { unsigned u; float f; } x; x.u = u << 16; return x.f;
}
static __device__ inline float bfhi(unsigned u) {
    union { unsigned u; float f; } x; x.u = u & 0xFFFF0000u; return x.f;
}
static __device__ inline short8 ld_frag(const unsigned* p) {
    union { unsigned u[4]; short8 v; } x;
    uint2 lo = *(const uint2*)p;
    uint2 hi = *(const uint2*)(p + 2);
    x.u[0] = lo.x; x.u[1] = lo.y; x.u[2] = hi.x; x.u[3] = hi.y;
    return x.v;
}

// ---- misc small kernels -------------------------------------------------
__global__ __launch_bounds__(256) void k_zero(float* p, int n) {
    int i = blockIdx.x * 256 + threadIdx.x;
    if (i < n) p[i] = 0.f;
}

__global__ __launch_bounds__(256) void k_stats(const float* __restrict__ obs,
                                               const float* __restrict__ act,
                                               float* __restrict__ gsum,
                                               float* __restrict__ gsq) {
    __shared__ float ssum[IN_N];
    __shared__ float ssq[IN_N];
    int a = blockIdx.x >> 5;
    int r0 = (blockIdx.x & 31) * 256;
    int t = threadIdx.x;
    if (t < IN_N) { ssum[t] = 0.f; ssq[t] = 0.f; }
    __syncthreads();
    if (t < 128) {
        const float* p = obs + ((size_t)a * B_N + r0) * O_N + t;
        float s = 0.f, q = 0.f;
#pragma unroll 4
        for (int r = 0; r < 256; ++r) {
            float v = p[(size_t)r * O_N];
            s += v; q += v * v;
        }
        ssum[t] = s; ssq[t] = q;
    } else {
        int tt = t - 128;
        int f = tt & 15, rg = tt >> 4;
        const float* p = act + ((size_t)a * B_N + r0 + rg) * ACT_N + f;
        float s = 0.f, q = 0.f;
#pragma unroll 4
        for (int i = 0; i < 32; ++i) {
            float v = p[(size_t)i * 8 * ACT_N];
            s += v; q += v * v;
        }
        atomicAdd(&ssum[O_N + f], s);
        atomicAdd(&ssq[O_N + f], q);
    }
    __syncthreads();
    if (t < IN_N) {
        atomicAdd(&gsum[a * IN_N + t], ssum[t]);
        atomicAdd(&gsq[a * IN_N + t], ssq[t]);
    }
}

__global__ __launch_bounds__(256) void k_finalize(float* gsum, float* gsq) {
    int i = blockIdx.x * 256 + threadIdx.x;
    if (i < A_N * IN_N) {
        const float invB = 1.f / (float)B_N;
        float m = gsum[i] * invB;
        float v = fmaxf(gsq[i] * invB - m * m, 0.f);
        gsum[i] = m;
        gsq[i] = rsqrtf(v + 1e-5f);
    }
}

// ---- weight prep: fp32 -> bf16, transposed to [n][k/2] packed uints -----
// wt_l1 rows pre-scaled by rstd (BN folded into weights).
#define L1E 393216
#define P1E 409600
#define P2E 417792
#define CRE 679936
__global__ __launch_bounds__(256) void k_wprep(
    const float* __restrict__ W_sa, const float* __restrict__ W_s,
    const float* __restrict__ Wk, const float* __restrict__ Wsel,
    const float* __restrict__ Wv, const float* __restrict__ Wc1,
    const float* __restrict__ rstd,
    unsigned* __restrict__ wt_l1, unsigned* __restrict__ wt_p1,
    unsigned* __restrict__ wt_p2, unsigned* __restrict__ wt_cr) {
    int idx = blockIdx.x * 256 + threadIdx.x;
    if (idx < L1E) {
        int a = idx / 24576, rem = idx % 24576;
        int n = rem & 255, kp = rem >> 8;  // kp 0..95
        int k0 = 2 * kp, k1 = k0 + 1;
        float v0 = 0.f, v1 = 0.f;
        if (n < 128) {
            if (k0 < IN_N) v0 = W_sa[((size_t)a * IN_N + k0) * H_N + n] * rstd[a * IN_N + k0];
            if (k1 < IN_N) v1 = W_sa[((size_t)a * IN_N + k1) * H_N + n] * rstd[a * IN_N + k1];
        } else {
            int m = n - 128;
            if (k0 < O_N) v0 = W_s[((size_t)a * O_N + k0) * H_N + m] * rstd[a * IN_N + k0];
            if (k1 < O_N) v1 = W_s[((size_t)a * O_N + k1) * H_N + m] * rstd[a * IN_N + k1];
        }
        wt_l1[(size_t)a * 24576 + n * 96 + kp] = pack_bf2(v0, v1);
    } else if (idx < P1E) {
        int i2 = idx - L1E;
        int n = i2 & 255, kp = i2 >> 8;
        int k0 = 2 * kp;
        float v0, v1;
        if (n < 128) {
            const float* w = Wk + ((size_t)(n >> 5) * H_N) * D_N + (n & 31);
            v0 = w[(size_t)k0 * D_N]; v1 = w[(size_t)(k0 + 1) * D_N];
        } else {
            int m = n - 128;
            const float* w = Wv + ((size_t)(m >> 5) * H_N) * D_N + (m & 31);
            v0 = w[(size_t)k0 * D_N]; v1 = w[(size_t)(k0 + 1) * D_N];
        }
        wt_p1[n * 64 + kp] = pack_bf2(v0, v1);
    } else if (idx < P2E) {
        int i3 = idx - P1E;
        int n = i3 & 127, kp = i3 >> 7;
        int k0 = 2 * kp;
        const float* w = Wsel + ((size_t)(n >> 5) * H_N) * D_N + (n & 31);
        wt_p2[n * 64 + kp] = pack_bf2(w[(size_t)k0 * D_N], w[(size_t)(k0 + 1) * D_N]);
    } else if (idx < CRE) {
        int i4 = idx - P2E;
        int a = i4 >> 14, r = i4 & 16383;
        int n = r & 127, kp = r >> 7;
        int k0 = 2 * kp;
        const float* w = Wc1 + (size_t)a * 256 * H_N + n;
        wt_cr[(size_t)a * 16384 + n * 128 + kp] =
            pack_bf2(w[(size_t)k0 * H_N], w[(size_t)(k0 + 1) * H_N]);
    }
}

// ---- folded biases: fb[0][a][c] = b_sa - sum(m*r*W_sa); fb[1] for se ----
__global__ __launch_bounds__(256) void k_bfold(
    const float* __restrict__ mean, const float* __restrict__ rstd,
    const float* __restrict__ W_sa, const float* __restrict__ W_s,
    const float* __restrict__ b_sa, const float* __restrict__ b_s,
    float* __restrict__ fb) {
    int a = blockIdx.x, c = threadIdx.x;
    float s = 0.f;
    if (c < 128) {
        for (int k = 0; k < IN_N; ++k)
            s += mean[a * IN_N + k] * rstd[a * IN_N + k] *
                 W_sa[((size_t)a * IN_N + k) * H_N + c];
        fb[a * 128 + c] = b_sa[a * H_N + c] - s;
    } else {
        int m = c - 128;
        for (int k = 0; k < O_N; ++k)
            s += mean[a * IN_N + k] * rstd[a * IN_N + k] *
                 W_s[((size_t)a * O_N + k) * H_N + m];
        fb[2048 + a * 128 + m] = b_s[a * H_N + m] - s;
    }
}

// ---- L1: z=0 -> sa (K=144 pad 160), z=1 -> se (K=128). BN pre-folded. ---
__global__ __launch_bounds__(256, 3) void k_l1(
    const float* __restrict__ obs, const float* __restrict__ act,
    const unsigned* __restrict__ wt_l1, const float* __restrict__ fb,
    unsigned short* __restrict__ sa_us, unsigned short* __restrict__ se_us,
    int b0g, int Bc) {
    __shared__ unsigned smem[(128 + 128) * 34];
    unsigned* Xs = smem;
    unsigned* Ws = smem + 128 * 34;

    int a = blockIdx.y;
    int z = blockIdx.z;
    int b0 = blockIdx.x * 128;
    int t = threadIdx.x;
    int wid = t >> 6, lane = t & 63, lm = lane & 15, lq = lane >> 4;
    int wrow = (wid & 1) * 64;
    int wcol = (wid >> 1) * 64;

    int kchunks = z ? 2 : 3;
    int kstop = z ? 128 : 160;
    const float* bias = fb + z * 2048 + a * 128;
    unsigned short* outp = z ? se_us : sa_us;

    floatx4 acc[4][4];
#pragma unroll
    for (int mt = 0; mt < 4; ++mt)
#pragma unroll
        for (int nt = 0; nt < 4; ++nt)
#pragma unroll
            for (int e = 0; e < 4; ++e) acc[mt][nt][e] = 0.f;

    const unsigned* WtA = wt_l1 + (size_t)a * 24576 + (size_t)(z * 128) * 96;

    for (int c = 0; c < kchunks; ++c) {
        int kk = c * 64;
        __syncthreads();
        for (int idx = t; idx < 128 * 32; idx += 256) {
            int r = idx >> 5, kp = idx & 31;
            int k = kk + 2 * kp;
            float v0 = 0.f, v1 = 0.f;
            size_t grow = (size_t)a * B_N + b0g + b0 + r;
            if (k < O_N) {
                v0 = obs[grow * O_N + k];
                v1 = obs[grow * O_N + k + 1];
            } else if (!z && k < IN_N) {
                v0 = act[grow * ACT_N + k - O_N];
                v1 = act[grow * ACT_N + k - O_N + 1];
            }
            Xs[r * 34 + kp] = pack_bf2(v0, v1);
        }
        for (int idx = t; idx < 128 * 32; idx += 256) {
            int n = idx >> 5, kp = idx & 31;
            Ws[n * 34 + kp] = WtA[(size_t)n * 96 + (kk >> 1) + kp];
        }
        __syncthreads();
#pragma unroll
        for (int s = 0; s < 2; ++s) {
            if (kk + s * 32 >= kstop) break;
            short8 afr[4];
#pragma unroll
            for (int mt = 0; mt < 4; ++mt)
                afr[mt] = ld_frag(&Xs[(wrow + mt * 16 + lm) * 34 + s * 16 + lq * 4]);
#pragma unroll
            for (int nt = 0; nt < 4; ++nt) {
                short8 bfr = ld_frag(&Ws[(wcol + nt * 16 + lm) * 34 + s * 16 + lq * 4]);
#pragma unroll
                for (int mt = 0; mt < 4; ++mt)
                    acc[mt][nt] = __builtin_amdgcn_mfma_f32_16x16x32_bf16(
                        afr[mt], bfr, acc[mt][nt], 0, 0, 0);
            }
        }
    }

#pragma unroll
    for (int mt = 0; mt < 4; ++mt)
#pragma unroll
        for (int nt = 0; nt < 4; ++nt)
#pragma unroll
            for (int r = 0; r < 4; ++r) {
                int row = b0 + wrow + mt * 16 + lq * 4 + r;
                int col = wcol + nt * 16 + lm;
                float v = acc[mt][nt][r] + bias[col];
                v = v > 0.f ? v : 0.01f * v;
                outp[((size_t)a * Bc + row) * 128 + col] = f2bf(v);
            }
}

// ---- fused: keys|vals|sel GEMMs (LDS-only) + MFMA QK^T + scalar PV ------
__global__ __launch_bounds__(256, 3) void k_fused(
    const unsigned* __restrict__ sa_u, const unsigned* __restrict__ se_u,
    const unsigned* __restrict__ wt_p1, const unsigned* __restrict__ wt_p2,
    const float* __restrict__ bv, unsigned short* __restrict__ other_us,
    int Bc) {
    __shared__ unsigned Xs[64 * 65];            // 16640 B (sa/se, then sel)
    __shared__ unsigned short keys_s[64 * 130]; // 16640 B (lg after QK^T)
    __shared__ unsigned short vals_s[64 * 136]; // 17408 B (16B-aligned rows)
    unsigned short* sel_s = (unsigned short*)Xs;

    int bg0 = blockIdx.x * 4;
    int t = threadIdx.x;
    int wid = t >> 6, lane = t & 63, lm = lane & 15, lq = lane >> 4;
    int wrow = (wid & 1) * 32;
    int wcol = (wid >> 1) * 64;

    // ---- load sa rows [64][64 uints], row = agent*4 + bsub ----
    for (int idx = t; idx < 64 * 64; idx += 256) {
        int r = idx >> 6, kp = idx & 63;
        int a = r >> 2, b = bg0 + (r & 3);
        Xs[r * 65 + kp] = sa_u[((size_t)a * Bc + b) * 64 + kp];
    }
    __syncthreads();

    // ---- GEMM pass 0: keys, pass 1: vals ----
#pragma unroll
    for (int pass = 0; pass < 2; ++pass) {
        floatx4 acc[2][4];
#pragma unroll
        for (int mt = 0; mt < 2; ++mt)
#pragma unroll
            for (int nt = 0; nt < 4; ++nt)
#pragma unroll
                for (int e = 0; e < 4; ++e) acc[mt][nt][e] = 0.f;
        const unsigned* wbase = wt_p1 + (size_t)(pass * 128) * 64;
#pragma unroll
        for (int s = 0; s < 4; ++s) {
            short8 afr[2];
#pragma unroll
            for (int mt = 0; mt < 2; ++mt)
                afr[mt] = ld_frag(&Xs[(wrow + mt * 16 + lm) * 65 + s * 16 + lq * 4]);
#pragma unroll
            for (int nt = 0; nt < 4; ++nt) {
                int col = wcol + nt * 16 + lm;
                short8 bfr = ld_frag(wbase + (size_t)col * 64 + s * 16 + lq * 4);
#pragma unroll
                for (int mt = 0; mt < 2; ++mt)
                    acc[mt][nt] = __builtin_amdgcn_mfma_f32_16x16x32_bf16(
                        afr[mt], bfr, acc[mt][nt], 0, 0, 0);
            }
        }
#pragma unroll
        for (int mt = 0; mt < 2; ++mt)
#pragma unroll
            for (int nt = 0; nt < 4; ++nt)
#pragma unroll
                for (int r = 0; r < 4; ++r) {
                    int row = wrow + mt * 16 + lq * 4 + r;
                    int col = wcol + nt * 16 + lm;
                    float v = acc[mt][nt][r];
                    if (pass == 0) {
                        keys_s[row * 130 + col] = f2bf(v);
                    } else {
                        v += bv[col];
                        v = v > 0.f ? v : 0.01f * v;
                        vals_s[row * 136 + col] = f2bf(v);
                    }
                }
    }
    __syncthreads();

    // ---- load se rows (overwrite sa) ----
    for (int idx = t; idx < 64 * 64; idx += 256) {
        int r = idx >> 6, kp = idx & 63;
        int a = r >> 2, b = bg0 + (r & 3);
        Xs[r * 65 + kp] = se_u[((size_t)a * Bc + b) * 64 + kp];
    }
    __syncthreads();

    // ---- GEMM2: sel ----
    {
        floatx4 acc[2][4];
#pragma unroll
        for (int mt = 0; mt < 2; ++mt)
#pragma unroll
            for (int nt = 0; nt < 4; ++nt)
#pragma unroll
                for (int e = 0; e < 4; ++e) acc[mt][nt][e] = 0.f;
#pragma unroll
        for (int s = 0; s < 4; ++s) {
            short8 afr[2];
#pragma unroll
            for (int mt = 0; mt < 2; ++mt)
                afr[mt] = ld_frag(&Xs[(wrow + mt * 16 + lm) * 65 + s * 16 + lq * 4]);
#pragma unroll
            for (int nt = 0; nt < 4; ++nt) {
                int col = wcol + nt * 16 + lm;
                short8 bfr = ld_frag(wt_p2 + (size_t)col * 64 + s * 16 + lq * 4);
#pragma unroll
                for (int mt = 0; mt < 2; ++mt)
                    acc[mt][nt] = __builtin_amdgcn_mfma_f32_16x16x32_bf16(
                        afr[mt], bfr, acc[mt][nt], 0, 0, 0);
            }
        }
        __syncthreads();  // all waves done reading Xs(se)
#pragma unroll
        for (int mt = 0; mt < 2; ++mt)
#pragma unroll
            for (int nt = 0; nt < 4; ++nt)
#pragma unroll
                for (int r = 0; r < 4; ++r) {
                    int row = wrow + mt * 16 + lq * 4 + r;
                    int col = wcol + nt * 16 + lm;
                    sel_s[row * 130 + col] = f2bf(acc[mt][nt][r]);
                }
    }
    __syncthreads();

    // ---- QK^T via MFMA: wave wid = bsub; one mfma per head n ----
    const unsigned* keysU = (const unsigned*)keys_s;
    floatx4 lgacc[4];
#pragma unroll
    for (int n = 0; n < 4; ++n) {
        short8 afr = ld_frag(&Xs[(lm * 4 + wid) * 65 + n * 16 + lq * 4]);     // sel
        short8 bfr = ld_frag(&keysU[(lm * 4 + wid) * 65 + n * 16 + lq * 4]);  // keys
        floatx4 z4 = {0.f, 0.f, 0.f, 0.f};
        lgacc[n] = __builtin_amdgcn_mfma_f32_16x16x32_bf16(afr, bfr, z4, 0, 0, 0);
    }
    __syncthreads();  // keys reads complete everywhere; reuse region for lg

    // lg layout: [(bsub*4+n)*16 + i][16 j] fp32 (16 KB in keys region)
    float* lgs = (float*)keys_s;
#pragma unroll
    for (int n = 0; n < 4; ++n)
#pragma unroll
        for (int r = 0; r < 4; ++r) {
            int i = lq * 4 + r;
            lgs[((wid * 4 + n) * 16 + i) * 16 + lm] =
                lgacc[n][r] * 0.17677669529663687f;
        }
    // wave-local readback (DS ops in-order per wave)

    int bsub = wid, n = (t >> 4) & 3, i = t & 15;
    float lg[16];
    {
        const float4* lgp = (const float4*)&lgs[((bsub * 4 + n) * 16 + i) * 16];
#pragma unroll
        for (int c = 0; c < 4; ++c) {
            float4 v = lgp[c];
            lg[4 * c] = v.x; lg[4 * c + 1] = v.y;
            lg[4 * c + 2] = v.z; lg[4 * c + 3] = v.w;
        }
    }
    lg[i] = NEGV;
    float m = lg[0];
#pragma unroll
    for (int j = 1; j < 16; ++j) m = fmaxf(m, lg[j]);
    float sum = 0.f;
#pragma unroll
    for (int j = 0; j < 16; ++j) { lg[j] = __expf(lg[j] - m); sum += lg[j]; }
    float inv = 1.f / sum;
#pragma unroll
    for (int j = 0; j < 16; ++j) lg[j] *= inv;

    // ---- PV: vals rows broadcast across agent lanes, uint4 reads ----
    const unsigned* valsU = (const unsigned*)vals_s;
    float ov[32];
#pragma unroll
    for (int u = 0; u < 32; ++u) ov[u] = 0.f;
#pragma unroll
    for (int j = 0; j < 16; ++j) {
        const uint4* vrow = (const uint4*)&valsU[(j * 4 + bsub) * 68 + n * 16];
        float w = lg[j];
#pragma unroll
        for (int c = 0; c < 4; ++c) {
            uint4 x = vrow[c];
            ov[8 * c + 0] = fmaf(w, bflo(x.x), ov[8 * c + 0]);
            ov[8 * c + 1] = fmaf(w, bfhi(x.x), ov[8 * c + 1]);
            ov[8 * c + 2] = fmaf(w, bflo(x.y), ov[8 * c + 2]);
            ov[8 * c + 3] = fmaf(w, bfhi(x.y), ov[8 * c + 3]);
            ov[8 * c + 4] = fmaf(w, bflo(x.z), ov[8 * c + 4]);
            ov[8 * c + 5] = fmaf(w, bfhi(x.z), ov[8 * c + 5]);
            ov[8 * c + 6] = fmaf(w, bflo(x.w), ov[8 * c + 6]);
            ov[8 * c + 7] = fmaf(w, bfhi(x.w), ov[8 * c + 7]);
        }
    }
    {
        uint4* orow = (uint4*)&other_us[((size_t)i * Bc + bg0 + bsub) * 128 + n * 32];
#pragma unroll
        for (int h = 0; h < 2; ++h) {
            uint4 o;
            o.x = pack_bf2(ov[16 * h + 0], ov[16 * h + 1]);
            o.y = pack_bf2(ov[16 * h + 2], ov[16 * h + 3]);
            o.z = pack_bf2(ov[16 * h + 4], ov[16 * h + 5]);
            o.w = pack_bf2(ov[16 * h + 6], ov[16 * h + 7]);
            orow[2 * h] = o;
            o.x = pack_bf2(ov[16 * h + 8], ov[16 * h + 9]);
            o.y = pack_bf2(ov[16 * h + 10], ov[16 * h + 11]);
            o.z = pack_bf2(ov[16 * h + 12], ov[16 * h + 13]);
            o.w = pack_bf2(ov[16 * h + 14], ov[16 * h + 15]);
            orow[2 * h + 1] = o;
        }
    }
}

// ---- critic: block 64 rows x 128 cols, wave 32x64, acc[2][4] ------------
__global__ __launch_bounds__(256, 3) void k_critic(
    const unsigned* __restrict__ se_u, const unsigned* __restrict__ other_u,
    const unsigned* __restrict__ wt_cr,
    const float* __restrict__ bc1, const float* __restrict__ actions,
    const float* __restrict__ Wc2, const float* __restrict__ bc2,
    float* __restrict__ qout, int b0g, int Bc) {
    __shared__ unsigned smem[(64 + 128) * 34];
    unsigned* Xs = smem;
    unsigned* Ws = smem + 64 * 34;

    int a = blockIdx.y;
    int b0 = blockIdx.x * 64;
    int t = threadIdx.x;
    int wid = t >> 6, lane = t & 63, lm = lane & 15, lq = lane >> 4;
    int wrow = (wid & 1) * 32;
    int wcol = (wid >> 1) * 64;

    floatx4 acc[2][4];
#pragma unroll
    for (int mt = 0; mt < 2; ++mt)
#pragma unroll
        for (int nt = 0; nt < 4; ++nt)
#pragma unroll
            for (int e = 0; e < 4; ++e) acc[mt][nt][e] = 0.f;

    const unsigned* WtA = wt_cr + (size_t)a * 16384;

    for (int c = 0; c < 4; ++c) {
        int kk = c * 64;
        __syncthreads();
        const unsigned* src = (c < 2) ? se_u : other_u;
        int off = (c & 1) * 32;
        for (int idx = t; idx < 64 * 32; idx += 256) {
            int r = idx >> 5, kp = idx & 31;
            Xs[r * 34 + kp] = src[((size_t)a * Bc + b0 + r) * 64 + off + kp];
        }
        for (int idx = t; idx < 128 * 32; idx += 256) {
            int n = idx >> 5, kp = idx & 31;
            Ws[n * 34 + kp] = WtA[(size_t)n * 128 + (kk >> 1) + kp];
        }
        __syncthreads();
#pragma unroll
        for (int s = 0; s < 2; ++s) {
            short8 afr[2];
#pragma unroll
            for (int mt = 0; mt < 2; ++mt)
                afr[mt] = ld_frag(&Xs[(wrow + mt * 16 + lm) * 34 + s * 16 + lq * 4]);
#pragma unroll
            for (int nt = 0; nt < 4; ++nt) {
                short8 bfr = ld_frag(&Ws[(wcol + nt * 16 + lm) * 34 + s * 16 + lq * 4]);
#pragma unroll
                for (int mt = 0; mt < 2; ++mt)
                    acc[mt][nt] = __builtin_amdgcn_mfma_f32_16x16x32_bf16(
                        afr[mt], bfr, acc[mt][nt], 0, 0, 0);
            }
        }
    }

    __syncthreads();
    unsigned short* hbuf = (unsigned short*)smem;  // [64][132]
#pragma unroll
    for (int mt = 0; mt < 2; ++mt)
#pragma unroll
        for (int nt = 0; nt < 4; ++nt)
#pragma unroll
            for (int r = 0; r < 4; ++r) {
                int row = wrow + mt * 16 + lq * 4 + r;
                int col = wcol + nt * 16 + lm;
                float v = acc[mt][nt][r] + bc1[a * H_N + col];
                v = v > 0.f ? v : 0.01f * v;
                hbuf[row * 132 + col] = f2bf(v);
            }
    __syncthreads();
    if (t < 64) {
        size_t arow = (size_t)a * B_N + b0g + b0 + t;
        const float* ap = &actions[arow * ACT_N];
        float bestv = ap[0];
        int bi = 0;
        for (int o = 1; o < ACT_N; ++o) {
            float v = ap[o];
            if (v > bestv) { bestv = v; bi = o; }
        }
        float q = bc2[a * ACT_N + bi];
        const float* w2 = &Wc2[((size_t)a * H_N) * ACT_N + bi];
        const unsigned short* hp = &hbuf[t * 132];
#pragma unroll 8
        for (int h = 0; h < H_N; ++h)
            q = fmaf(bf2f(hp[h]), w2[(size_t)h * ACT_N], q);
        qout[arow] = q;
    }
}

extern "C" void kernel_launch(void* const* d_in, const int* in_sizes, int n_in,
                              void* d_out, int out_size, void* d_ws, size_t ws_size,
                              hipStream_t stream) {
    const float* obs     = (const float*)d_in[0];
    const float* actions = (const float*)d_in[1];
    const float* W_sa    = (const float*)d_in[2];
    const float* b_sa    = (const float*)d_in[3];
    const float* W_s     = (const float*)d_in[4];
    const float* b_s     = (const float*)d_in[5];
    const float* Wk      = (const float*)d_in[6];
    const float* Wsel    = (const float*)d_in[7];
    const float* Wv      = (const float*)d_in[8];
    const float* bv      = (const float*)d_in[9];
    const float* Wc1     = (const float*)d_in[10];
    const float* bc1     = (const float*)d_in[11];
    const float* Wc2     = (const float*)d_in[12];
    const float* bc2     = (const float*)d_in[13];
    float* out = (float*)d_out;
    char* ws = (char*)d_ws;

    size_t o = 0;
    float* gsum = (float*)(ws + o); o += 2304 * 4;
    float* gsq  = (float*)(ws + o); o += 2304 * 4;
    unsigned* wt_l1 = (unsigned*)(ws + o); o += (size_t)393216 * 4;
    unsigned* wt_p1 = (unsigned*)(ws + o); o += (size_t)16384 * 4;
    unsigned* wt_p2 = (unsigned*)(ws + o); o += (size_t)8192 * 4;
    unsigned* wt_cr = (unsigned*)(ws + o); o += (size_t)262144 * 4;
    float* fb = (float*)(ws + o); o += (size_t)4096 * 4;
    size_t fixed = o;

    int Bc = B_N;
    while (Bc > 128 && fixed + 12288ull * Bc > ws_size) Bc >>= 1;

    unsigned short* sa_us = (unsigned short*)(ws + o); o += (size_t)A_N * Bc * 128 * 2;
    unsigned short* se_us = (unsigned short*)(ws + o); o += (size_t)A_N * Bc * 128 * 2;
    unsigned short* ot_us = (unsigned short*)(ws + o); o += (size_t)A_N * Bc * 128 * 2;

    k_zero<<<dim3(18), 256, 0, stream>>>(gsum, 2 * A_N * IN_N);
    k_stats<<<dim3(A_N * 32), 256, 0, stream>>>(obs, actions, gsum, gsq);
    k_finalize<<<dim3(9), 256, 0, stream>>>(gsum, gsq);
    k_wprep<<<dim3(CRE / 256), 256, 0, stream>>>(W_sa, W_s, Wk, Wsel, Wv, Wc1,
                                                 gsq, wt_l1, wt_p1, wt_p2, wt_cr);
    k_bfold<<<dim3(A_N), 256, 0, stream>>>(gsum, gsq, W_sa, W_s, b_sa, b_s, fb);

    for (int b0g = 0; b0g < B_N; b0g += Bc) {
        k_l1<<<dim3(Bc / 128, A_N, 2), 256, 0, stream>>>(
            obs, actions, wt_l1, fb, sa_us, se_us, b0g, Bc);
        k_fused<<<dim3(Bc / 4), 256, 0, stream>>>(
            (const unsigned*)sa_us, (const unsigned*)se_us, wt_p1, wt_p2, bv,
            ot_us, Bc);
        k_critic<<<dim3(Bc / 64, A_N), 256, 0, stream>>>(
            (const unsigned*)se_us, (const unsigned*)ot_us, wt_cr, bc1,
            actions, Wc2, bc2, out, b0g, Bc);
    }
}